// Round 9
// baseline (344.428 us; speedup 1.0000x reference)
//
#include <hip/hip_runtime.h>
#include <math.h>

#define SEQ 2048
#define DMODEL 1024
#define DIN 2048
#define NST 16
#define DTR 64
#define CH 64
#define NCH (SEQ / CH)

typedef __attribute__((ext_vector_type(8))) short bf16x8;
typedef __attribute__((ext_vector_type(4))) float f32x4;

__device__ __forceinline__ ushort f2bf(float f) {
  union { float f; unsigned u; } c; c.f = f;
  return (ushort)((c.u + 0x7fffu + ((c.u >> 16) & 1u)) >> 16);
}
__device__ __forceinline__ float bf2f(ushort h) {
  union { unsigned u; float f; } c; c.u = ((unsigned)h) << 16;
  return c.f;
}
__device__ __forceinline__ float splus(float v) {
  return v > 20.f ? v : log1pf(__expf(v));
}
// p[n] = e^(n+1), depth-4 mul tree (no transcendentals).
__device__ __forceinline__ void powers16(float e, float* p) {
  float e2 = e * e, e4 = e2 * e2, e8 = e4 * e4;
  p[0] = e;       p[1] = e2;       p[2] = e2 * e;   p[3] = e4;
  p[4] = e4 * e;  p[5] = e4 * e2;  p[6] = e4 * p[2]; p[7] = e8;
  p[8] = e8 * e;  p[9] = e8 * e2;  p[10] = e8 * p[2]; p[11] = e8 * e4;
  p[12] = e8 * p[4]; p[13] = e8 * p[5]; p[14] = e8 * p[6]; p[15] = e8 * e8;
}

#define GLL(g, l) __builtin_amdgcn_global_load_lds( \
    (const __attribute__((address_space(1))) void*)(g), \
    (__attribute__((address_space(3))) void*)(l), 16, 0, 0)

// =====================================================================
// Split-bf16 3-pass MFMA GEMM (fp32-accurate).  C[m,n]=sum_k A[m,k]B[n,k]
// Staging: burst-coalesced global lane map + XOR swizzle of the 16B
// k-chunk (phys = c ^ ((r>>1)&3)); fragment reads 2-way = free.
// =====================================================================
template<int BM, int BN, int SPLITK>
__global__ __launch_bounds__(256) void gemm3p(const ushort* __restrict__ Ahi,
                                              const ushort* __restrict__ Alo,
                                              const ushort* __restrict__ Bhi,
                                              const ushort* __restrict__ Blo,
                                              float* __restrict__ C,
                                              int M, int N, int K) {
  constexpr int BK = 32;
  constexpr int WM = BM / 2, WN = BN / 2, TM = WM / 16, TN = WN / 16;
  constexpr int SA = BM / 16, SB = BN / 16;
  __shared__ __align__(16) ushort sAh[BM * BK], sAl[BM * BK];
  __shared__ __align__(16) ushort sBh[BN * BK], sBl[BN * BK];
  const int tid = threadIdx.x, wid = tid >> 6, lane = tid & 63;
  const int m0 = blockIdx.y * BM, n0 = blockIdx.x * BN;
  const int Kc = K / SPLITK, kbeg = blockIdx.z * Kc;
  const int wm0 = (wid >> 1) * WM, wn0 = (wid & 1) * WN;
  const int fr = lane & 15;
  const int lrow = lane >> 2;
  const int lkc = (lane & 3) ^ ((lane >> 3) & 3);
  const int fpo = fr * 32 + (((lane >> 4) ^ ((lane >> 1) & 3)) * 8);

  f32x4 acc[TM][TN];
#pragma unroll
  for (int mi = 0; mi < TM; ++mi)
#pragma unroll
    for (int ni = 0; ni < TN; ++ni)
#pragma unroll
      for (int r = 0; r < 4; ++r) acc[mi][ni][r] = 0.f;

  for (int k0 = 0; k0 < Kc; k0 += BK) {
    __syncthreads();
    const int kg = kbeg + k0 + lkc * 8;
#pragma unroll
    for (int i = 0; i < SA / 4; ++i) {
      const int seg = wid * (SA / 4) + i;
      const size_t ga = (size_t)(m0 + seg * 16 + lrow) * K + kg;
      GLL(&Ahi[ga], &sAh[seg * 512]);
      GLL(&Alo[ga], &sAl[seg * 512]);
    }
#pragma unroll
    for (int i = 0; i < SB / 4; ++i) {
      const int seg = wid * (SB / 4) + i;
      const size_t ga = (size_t)(n0 + seg * 16 + lrow) * K + kg;
      GLL(&Bhi[ga], &sBh[seg * 512]);
      GLL(&Blo[ga], &sBl[seg * 512]);
    }
    __syncthreads();

    bf16x8 ah[TM], al[TM], bh[TN], bl[TN];
#pragma unroll
    for (int mi = 0; mi < TM; ++mi) {
      const int r = (wm0 / 16 + mi) * 512 + fpo;
      ah[mi] = *(const bf16x8*)&sAh[r];
      al[mi] = *(const bf16x8*)&sAl[r];
    }
#pragma unroll
    for (int ni = 0; ni < TN; ++ni) {
      const int r = (wn0 / 16 + ni) * 512 + fpo;
      bh[ni] = *(const bf16x8*)&sBh[r];
      bl[ni] = *(const bf16x8*)&sBl[r];
    }
#pragma unroll
    for (int mi = 0; mi < TM; ++mi)
#pragma unroll
      for (int ni = 0; ni < TN; ++ni) {
        acc[mi][ni] = __builtin_amdgcn_mfma_f32_16x16x32_bf16(ah[mi], bh[ni], acc[mi][ni], 0, 0, 0);
        acc[mi][ni] = __builtin_amdgcn_mfma_f32_16x16x32_bf16(ah[mi], bl[ni], acc[mi][ni], 0, 0, 0);
        acc[mi][ni] = __builtin_amdgcn_mfma_f32_16x16x32_bf16(al[mi], bh[ni], acc[mi][ni], 0, 0, 0);
      }
  }

  float* __restrict__ Co = C + (size_t)blockIdx.z * M * N;
#pragma unroll
  for (int mi = 0; mi < TM; ++mi)
#pragma unroll
    for (int ni = 0; ni < TN; ++ni)
#pragma unroll
      for (int r = 0; r < 4; ++r)
        Co[(size_t)(m0 + wm0 + mi * 16 + (lane >> 4) * 4 + r) * N + n0 + wn0 + ni * 16 + fr] =
            acc[mi][ni][r];
}

__device__ __forceinline__ void split_store4(float4 v, ushort* hi, ushort* lo, size_t i) {
  ushort h0 = f2bf(v.x), h1 = f2bf(v.y), h2 = f2bf(v.z), h3 = f2bf(v.w);
  *(ushort4*)&hi[i] = make_ushort4(h0, h1, h2, h3);
  *(ushort4*)&lo[i] = make_ushort4(f2bf(v.x - bf2f(h0)), f2bf(v.y - bf2f(h1)),
                                   f2bf(v.z - bf2f(h2)), f2bf(v.w - bf2f(h3)));
}

// One launch converting in_proj_w, hidden, x1w, x2w -> bf16 hi/lo planes.
__global__ __launch_bounds__(256) void cvt_fused(const float* __restrict__ inw,
                                                 const float* __restrict__ hid,
                                                 const float* __restrict__ x1w,
                                                 const float* __restrict__ x2w,
                                                 ushort* __restrict__ w_hi, ushort* __restrict__ w_lo,
                                                 ushort* __restrict__ h_hi, ushort* __restrict__ h_lo,
                                                 ushort* __restrict__ wx_hi, ushort* __restrict__ wx_lo) {
  const int q = blockIdx.x * 256 + threadIdx.x;  // float4 index
  const float* src; ushort* dhi; ushort* dlo; int base;
  if (q < 1048576)            { src = inw; dhi = w_hi;  dlo = w_lo;  base = q; }
  else if (q < 1572864)       { src = hid; dhi = h_hi;  dlo = h_lo;  base = q - 1048576; }
  else if (q < 1622016)       { src = x1w; dhi = wx_hi; dlo = wx_lo; base = q - 1572864; }
  else                        { src = x2w; dhi = wx_hi + 196608; dlo = wx_lo + 196608; base = q - 1622016; }
  const size_t i = (size_t)base * 4;
  split_store4(*(const float4*)&src[i], dhi, dlo, i);
}

__global__ __launch_bounds__(256) void cvt_split(const float* __restrict__ x,
                                                 ushort* __restrict__ hi,
                                                 ushort* __restrict__ lo, int n) {
  const int i = (blockIdx.x * 256 + threadIdx.x) * 4;
  if (i >= n) return;
  split_store4(*(const float4*)&x[i], hi, lo, i);
}

__global__ __launch_bounds__(256) void reduce_out(const float* __restrict__ p,
                                                  float* __restrict__ o, int n) {
  const int i = (blockIdx.x * 256 + threadIdx.x) * 4;
  if (i >= n) return;
  float4 a = *(const float4*)&p[i];
  float4 b = *(const float4*)&p[(size_t)n + i];
  float4 c = *(const float4*)&p[(size_t)2 * n + i];
  float4 d = *(const float4*)&p[(size_t)3 * n + i];
  *(float4*)&o[i] = make_float4(a.x + b.x + c.x + d.x, a.y + b.y + c.y + d.y,
                                a.z + b.z + c.z + d.z, a.w + b.w + c.w + d.w);
}

// =====================================================================
// Conv (w=4, causal) + bias + SiLU -> transposed bf16 hi/lo planes (l,d).
// =====================================================================
__global__ __launch_bounds__(256) void conv_tr_kernel(const float* __restrict__ xz,
                                                      const float* __restrict__ cw,
                                                      const float* __restrict__ cb,
                                                      ushort* __restrict__ xcT_hi,
                                                      ushort* __restrict__ xcT_lo) {
  const int l0 = blockIdx.x * 64, d0 = blockIdx.y * 64;
  const int tid = threadIdx.x;
  __shared__ float xin[64][68];  // cols 0..66 = l0-3 .. l0+63
  __shared__ float To[64][65];
  __shared__ float cwS[64][4];
  __shared__ float cbS[64];

  for (int i = tid; i < 1024; i += 256) {
    const int d = i >> 4, q = i & 15;
    float4 v = *(const float4*)&xz[(size_t)(d0 + d) * SEQ + l0 + q * 4];
    xin[d][3 + q * 4 + 0] = v.x; xin[d][3 + q * 4 + 1] = v.y;
    xin[d][3 + q * 4 + 2] = v.z; xin[d][3 + q * 4 + 3] = v.w;
  }
  if (tid < 192) {
    const int j = tid >> 6, d = tid & 63;
    const int l = l0 - 3 + j;
    xin[d][j] = (l >= 0) ? xz[(size_t)(d0 + d) * SEQ + l] : 0.f;
  }
  if (tid < 64) {
    cbS[tid] = cb[d0 + tid];
    float4 w = *(const float4*)&cw[(d0 + tid) * 4];
    cwS[tid][0] = w.x; cwS[tid][1] = w.y; cwS[tid][2] = w.z; cwS[tid][3] = w.w;
  }
  __syncthreads();

  for (int i = tid; i < 4096; i += 256) {
    const int d = i >> 6, l = i & 63;
    float a = cbS[d] + cwS[d][0] * xin[d][l] + cwS[d][1] * xin[d][l + 1] +
              cwS[d][2] * xin[d][l + 2] + cwS[d][3] * xin[d][l + 3];
    To[d][l] = a / (1.f + __expf(-a));
  }
  __syncthreads();

  for (int i = tid; i < 4096; i += 256) {
    const int l = i >> 6, dd = i & 63;
    float v = To[dd][l];  // stride-65: conflict-free
    ushort h = f2bf(v);
    xcT_hi[(size_t)(l0 + l) * DIN + d0 + dd] = h;
    xcT_lo[(size_t)(l0 + l) * DIN + d0 + dd] = f2bf(v - bf2f(h));
  }
}

// silu(z) transposed to (l,d) fp32 for the fused scan epilogue.
__global__ __launch_bounds__(256) void z_tr_kernel(const float* __restrict__ xz,
                                                   float* __restrict__ zT) {
  const int l0 = blockIdx.x * 64, d0 = blockIdx.y * 64;
  const int tid = threadIdx.x;
  __shared__ float Tz[64][65];
  for (int i = tid; i < 1024; i += 256) {
    const int d = i >> 4, q = i & 15;
    float4 v = *(const float4*)&xz[(size_t)(DIN + d0 + d) * SEQ + l0 + q * 4];
    Tz[d][q * 4 + 0] = v.x / (1.f + __expf(-v.x));
    Tz[d][q * 4 + 1] = v.y / (1.f + __expf(-v.y));
    Tz[d][q * 4 + 2] = v.z / (1.f + __expf(-v.z));
    Tz[d][q * 4 + 3] = v.w / (1.f + __expf(-v.w));
  }
  __syncthreads();
  for (int i = tid; i < 1024; i += 256) {
    const int l = i >> 4, dc = (i & 15) * 4;
    *(float4*)&zT[(size_t)(l0 + l) * DIN + d0 + dc] =
        make_float4(Tz[dc + 0][l], Tz[dc + 1][l], Tz[dc + 2][l], Tz[dc + 3][l]);
  }
}

// Reduce 8 x_proj split-K slabs (192 x SEQ) -> dblS; emit B/C (l,n) tables.
__global__ __launch_bounds__(256) void reduce_dblS_kernel(const float* __restrict__ p,
                                                          float* __restrict__ o,
                                                          float* __restrict__ BT1,
                                                          float* __restrict__ CT1,
                                                          float* __restrict__ BT2,
                                                          float* __restrict__ CT2) {
  const int NE = 192 * SEQ;
  const int idx = blockIdx.x * 256 + threadIdx.x;
  float s = 0.f;
#pragma unroll
  for (int cc = 0; cc < 8; ++cc) s += p[(size_t)cc * NE + idx];
  o[idx] = s;
  const int k = idx >> 11, l = idx & (SEQ - 1);
  if (k >= 64 && k < 80)        BT1[l * NST + (k - 64)] = s;
  else if (k >= 80 && k < 96)   CT1[l * NST + (k - 80)] = s;
  else if (k >= 160 && k < 176) BT2[l * NST + (k - 160)] = s;
  else if (k >= 176)            CT2[l * NST + (k - 176)] = s;
}

// =====================================================================
// dt GEMM + fused softplus(dt+bias); output sp in (l,d) layout.
// =====================================================================
__global__ __launch_bounds__(256) void dt_gemm_kernel(const float* __restrict__ dbl1,
                                                      const float* __restrict__ dbl2,
                                                      const float* __restrict__ w1,
                                                      const float* __restrict__ w2,
                                                      const float* __restrict__ b1,
                                                      const float* __restrict__ b2,
                                                      float* __restrict__ o1,
                                                      float* __restrict__ o2) {
  const int br = blockIdx.z;
  const float* __restrict__ dbl = br ? dbl2 : dbl1;
  const float* __restrict__ W = br ? w2 : w1;
  const float* __restrict__ dtb = br ? b2 : b1;
  float* __restrict__ outp = br ? o2 : o1;
  const int l0 = blockIdx.x * 64, d0 = blockIdx.y * 64;
  __shared__ __align__(16) float Wt[64][68];
  __shared__ __align__(16) float Bs[64][68];
  const int tid = threadIdx.x;
  for (int i = tid; i < 4096; i += 256) {
    int a = i >> 6, b = i & 63;
    Wt[b][a] = W[(size_t)(d0 + a) * DTR + b];
    Bs[a][b] = dbl[(size_t)a * SEQ + l0 + b];
  }
  __syncthreads();
  const int tl_ = tid >> 4, td_ = tid & 15;
  float acc[4][4];  // [i: l][j: d]
#pragma unroll
  for (int i = 0; i < 4; ++i)
#pragma unroll
    for (int j = 0; j < 4; ++j) acc[i][j] = 0.f;
  for (int r = 0; r < 64; ++r) {
    float4 av = *(const float4*)&Bs[r][tl_ * 4];
    float4 bv = *(const float4*)&Wt[r][td_ * 4];
    float am[4] = {av.x, av.y, av.z, av.w};
    float bn[4] = {bv.x, bv.y, bv.z, bv.w};
#pragma unroll
    for (int i = 0; i < 4; ++i)
#pragma unroll
      for (int j = 0; j < 4; ++j) acc[i][j] = fmaf(am[i], bn[j], acc[i][j]);
  }
  const float4 bias4 = *(const float4*)&dtb[d0 + td_ * 4];
#pragma unroll
  for (int i = 0; i < 4; ++i) {
    float4 w = make_float4(splus(acc[i][0] + bias4.x), splus(acc[i][1] + bias4.y),
                           splus(acc[i][2] + bias4.z), splus(acc[i][3] + bias4.w));
    *(float4*)&outp[(size_t)(l0 + tl_ * 4 + i) * DIN + d0 + td_ * 4] = w;
  }
}

// =====================================================================
// Chunked selective scan.  All per-timestep inputs in (l,d) layout ->
// coalesced scalar loads.  u = hi+lo bf16 reconstruction (2^-18 exact).
// dA_n = exp(-k_n*sp); fast path when k_n == n+1 (one exp + mul tree).
// =====================================================================
__global__ __launch_bounds__(256) void scan_phase_a(const ushort* __restrict__ uhi,
                                                    const ushort* __restrict__ ulo,
                                                    const float* __restrict__ sp1T,
                                                    const float* __restrict__ sp2T,
                                                    const float* __restrict__ BT1,
                                                    const float* __restrict__ BT2,
                                                    const float* __restrict__ Al1,
                                                    const float* __restrict__ Al2,
                                                    float* __restrict__ hend,
                                                    float* __restrict__ Pend) {
  const int br = blockIdx.z;
  const float* __restrict__ spp = br ? sp2T : sp1T;
  const float* __restrict__ BT = br ? BT2 : BT1;
  const float* __restrict__ Al = br ? Al2 : Al1;
  const int c = blockIdx.y;
  const int t0 = c * CH;
  const int d = blockIdx.x * 256 + threadIdx.x;
  const size_t gbase = (size_t)t0 * DIN + d;

  __shared__ __align__(16) float Bs[CH][NST];
  ((float4*)Bs)[threadIdx.x] = ((const float4*)&BT[t0 * NST])[threadIdx.x];
  __syncthreads();

  bool fast = true;
#pragma unroll
  for (int n = 0; n < NST; ++n) {
    float kx = __expf(Al[(size_t)d * NST + n]);
    fast = fast && (fabsf(kx - (float)(n + 1)) < 1e-3f);
  }
  float h[NST];
#pragma unroll
  for (int n = 0; n < NST; ++n) h[n] = 0.f;
  float S = 0.f;

  if (fast) {
    for (int tt = 0; tt < CH / 4; ++tt) {
      float sparr[4], uarr[4];
#pragma unroll
      for (int j = 0; j < 4; ++j) {
        const size_t idx = gbase + (size_t)(tt * 4 + j) * DIN;
        sparr[j] = spp[idx];
        uarr[j] = bf2f(uhi[idx]) + bf2f(ulo[idx]);
      }
#pragma unroll
      for (int j = 0; j < 4; ++j) {
        const int t = tt * 4 + j;
        const float sp = sparr[j];
        S += sp;
        const float spu = sp * uarr[j];
        const float e = __expf(-sp);
        float p[NST];
        powers16(e, p);
#pragma unroll
        for (int ng = 0; ng < 4; ++ng) {
          float4 bq = *(const float4*)&Bs[t][ng * 4];
          float bf[4] = {bq.x, bq.y, bq.z, bq.w};
#pragma unroll
          for (int k = 0; k < 4; ++k) {
            int n = ng * 4 + k;
            h[n] = fmaf(p[n], h[n], spu * bf[k]);
          }
        }
      }
    }
  } else {
    float AnL2[NST];
#pragma unroll
    for (int n = 0; n < NST; ++n)
      AnL2[n] = -__expf(Al[(size_t)d * NST + n]) * 1.4426950408889634f;
    for (int tt = 0; tt < CH / 4; ++tt) {
      float sparr[4], uarr[4];
#pragma unroll
      for (int j = 0; j < 4; ++j) {
        const size_t idx = gbase + (size_t)(tt * 4 + j) * DIN;
        sparr[j] = spp[idx];
        uarr[j] = bf2f(uhi[idx]) + bf2f(ulo[idx]);
      }
#pragma unroll
      for (int j = 0; j < 4; ++j) {
        const int t = tt * 4 + j;
        const float sp = sparr[j];
        S += sp;
        const float spu = sp * uarr[j];
#pragma unroll
        for (int ng = 0; ng < 4; ++ng) {
          float4 bq = *(const float4*)&Bs[t][ng * 4];
          float bf[4] = {bq.x, bq.y, bq.z, bq.w};
#pragma unroll
          for (int k = 0; k < 4; ++k) {
            int n = ng * 4 + k;
            float dA = exp2f(AnL2[n] * sp);
            h[n] = fmaf(dA, h[n], spu * bf[k]);
          }
        }
      }
    }
  }

  float P[NST];
  if (fast) {
    powers16(__expf(-S), P);
  } else {
#pragma unroll
    for (int n = 0; n < NST; ++n)
      P[n] = exp2f(-__expf(Al[(size_t)d * NST + n]) * 1.4426950408889634f * S);
  }
  size_t base = ((size_t)(br * NCH + c) * DIN + d) * NST;
#pragma unroll
  for (int n = 0; n < NST; n += 4) {
    *(float4*)&hend[base + n] = make_float4(h[n], h[n + 1], h[n + 2], h[n + 3]);
    *(float4*)&Pend[base + n] = make_float4(P[n], P[n + 1], P[n + 2], P[n + 3]);
  }
}

// Carry across chunks; hin overwrites Pend in place (read P first).
__global__ __launch_bounds__(256) void scan_carry(const float* __restrict__ hend,
                                                  float* __restrict__ PendHin) {
  const int flat = blockIdx.x * 256 + threadIdx.x;
  const int br = flat >> 15;
  const int dn = flat & 32767;
  float h = 0.f;
  for (int c = 0; c < NCH; ++c) {
    size_t idx = ((size_t)(br * NCH + c) << 15) + dn;
    float Pv = PendHin[idx];
    float he = hend[idx];
    PendHin[idx] = h;
    h = fmaf(Pv, h, he);
  }
}

// Phase C, BOTH branches per thread: yd = (y1+D1u)-(y2+D2u), *silu(z),
// written directly as bf16 hi/lo planes for out_proj.  Kills the y1t/y2t
// round-trip and the separate ydiff kernel.
__global__ __launch_bounds__(256) void scan_phase_c_fused(
    const ushort* __restrict__ uhi, const ushort* __restrict__ ulo,
    const float* __restrict__ sp1T, const float* __restrict__ sp2T,
    const float* __restrict__ BT1, const float* __restrict__ CT1,
    const float* __restrict__ BT2, const float* __restrict__ CT2,
    const float* __restrict__ Al1, const float* __restrict__ Al2,
    const float* __restrict__ D1, const float* __restrict__ D2,
    const float* __restrict__ hin, const float* __restrict__ zT,
    ushort* __restrict__ yd_hi, ushort* __restrict__ yd_lo) {
  const int c = blockIdx.y;
  const int t0 = c * CH;
  const int d = blockIdx.x * 256 + threadIdx.x;
  const size_t gbase = (size_t)t0 * DIN + d;

  __shared__ __align__(16) float Bs1[CH][NST], Cs1[CH][NST];
  __shared__ __align__(16) float Bs2[CH][NST], Cs2[CH][NST];
  ((float4*)Bs1)[threadIdx.x] = ((const float4*)&BT1[t0 * NST])[threadIdx.x];
  ((float4*)Cs1)[threadIdx.x] = ((const float4*)&CT1[t0 * NST])[threadIdx.x];
  ((float4*)Bs2)[threadIdx.x] = ((const float4*)&BT2[t0 * NST])[threadIdx.x];
  ((float4*)Cs2)[threadIdx.x] = ((const float4*)&CT2[t0 * NST])[threadIdx.x];
  __syncthreads();

  bool fast = true;
#pragma unroll
  for (int n = 0; n < NST; ++n) {
    float k1 = __expf(Al1[(size_t)d * NST + n]);
    float k2 = __expf(Al2[(size_t)d * NST + n]);
    fast = fast && (fabsf(k1 - (float)(n + 1)) < 1e-3f) &&
           (fabsf(k2 - (float)(n + 1)) < 1e-3f);
  }
  const float Dd1 = D1[d], Dd2 = D2[d];
  float h1[NST], h2[NST];
  const size_t hb1 = ((size_t)c * DIN + d) * NST;
  const size_t hb2 = ((size_t)(NCH + c) * DIN + d) * NST;
#pragma unroll
  for (int n = 0; n < NST; n += 4) {
    float4 v1 = *(const float4*)&hin[hb1 + n];
    float4 v2 = *(const float4*)&hin[hb2 + n];
    h1[n] = v1.x; h1[n + 1] = v1.y; h1[n + 2] = v1.z; h1[n + 3] = v1.w;
    h2[n] = v2.x; h2[n + 1] = v2.y; h2[n + 2] = v2.z; h2[n + 3] = v2.w;
  }

  if (fast) {
    for (int tt = 0; tt < CH / 4; ++tt) {
      float sp1a[4], sp2a[4], uarr[4], zarr[4];
#pragma unroll
      for (int j = 0; j < 4; ++j) {
        const size_t idx = gbase + (size_t)(tt * 4 + j) * DIN;
        sp1a[j] = sp1T[idx];
        sp2a[j] = sp2T[idx];
        uarr[j] = bf2f(uhi[idx]) + bf2f(ulo[idx]);
        zarr[j] = zT[idx];
      }
#pragma unroll
      for (int j = 0; j < 4; ++j) {
        const int t = tt * 4 + j;
        const float uu = uarr[j];
        const float spu1 = sp1a[j] * uu, spu2 = sp2a[j] * uu;
        float p1[NST], p2[NST];
        powers16(__expf(-sp1a[j]), p1);
        powers16(__expf(-sp2a[j]), p2);
        float y1 = 0.f, y2 = 0.f;
#pragma unroll
        for (int ng = 0; ng < 4; ++ng) {
          float4 b1 = *(const float4*)&Bs1[t][ng * 4];
          float4 c1 = *(const float4*)&Cs1[t][ng * 4];
          float4 b2 = *(const float4*)&Bs2[t][ng * 4];
          float4 c2 = *(const float4*)&Cs2[t][ng * 4];
          float b1f[4] = {b1.x, b1.y, b1.z, b1.w};
          float c1f[4] = {c1.x, c1.y, c1.z, c1.w};
          float b2f[4] = {b2.x, b2.y, b2.z, b2.w};
          float c2f[4] = {c2.x, c2.y, c2.z, c2.w};
#pragma unroll
          for (int k = 0; k < 4; ++k) {
            int n = ng * 4 + k;
            h1[n] = fmaf(p1[n], h1[n], spu1 * b1f[k]);
            y1 = fmaf(h1[n], c1f[k], y1);
            h2[n] = fmaf(p2[n], h2[n], spu2 * b2f[k]);
            y2 = fmaf(h2[n], c2f[k], y2);
          }
        }
        const float v = ((y1 + Dd1 * uu) - (y2 + Dd2 * uu)) * zarr[j];
        const size_t oi = gbase + (size_t)t * DIN;
        ushort hh = f2bf(v);
        yd_hi[oi] = hh;
        yd_lo[oi] = f2bf(v - bf2f(hh));
      }
    }
  } else {
    float A1L2[NST], A2L2[NST];
#pragma unroll
    for (int n = 0; n < NST; ++n) {
      A1L2[n] = -__expf(Al1[(size_t)d * NST + n]) * 1.4426950408889634f;
      A2L2[n] = -__expf(Al2[(size_t)d * NST + n]) * 1.4426950408889634f;
    }
    for (int tt = 0; tt < CH / 4; ++tt) {
      float sp1a[4], sp2a[4], uarr[4], zarr[4];
#pragma unroll
      for (int j = 0; j < 4; ++j) {
        const size_t idx = gbase + (size_t)(tt * 4 + j) * DIN;
        sp1a[j] = sp1T[idx];
        sp2a[j] = sp2T[idx];
        uarr[j] = bf2f(uhi[idx]) + bf2f(ulo[idx]);
        zarr[j] = zT[idx];
      }
#pragma unroll
      for (int j = 0; j < 4; ++j) {
        const int t = tt * 4 + j;
        const float uu = uarr[j];
        const float spu1 = sp1a[j] * uu, spu2 = sp2a[j] * uu;
        float y1 = 0.f, y2 = 0.f;
#pragma unroll
        for (int ng = 0; ng < 4; ++ng) {
          float4 b1 = *(const float4*)&Bs1[t][ng * 4];
          float4 c1 = *(const float4*)&Cs1[t][ng * 4];
          float4 b2 = *(const float4*)&Bs2[t][ng * 4];
          float4 c2 = *(const float4*)&Cs2[t][ng * 4];
          float b1f[4] = {b1.x, b1.y, b1.z, b1.w};
          float c1f[4] = {c1.x, c1.y, c1.z, c1.w};
          float b2f[4] = {b2.x, b2.y, b2.z, b2.w};
          float c2f[4] = {c2.x, c2.y, c2.z, c2.w};
#pragma unroll
          for (int k = 0; k < 4; ++k) {
            int n = ng * 4 + k;
            float dA1 = exp2f(A1L2[n] * sp1a[j]);
            float dA2 = exp2f(A2L2[n] * sp2a[j]);
            h1[n] = fmaf(dA1, h1[n], spu1 * b1f[k]);
            y1 = fmaf(h1[n], c1f[k], y1);
            h2[n] = fmaf(dA2, h2[n], spu2 * b2f[k]);
            y2 = fmaf(h2[n], c2f[k], y2);
          }
        }
        const float v = ((y1 + Dd1 * uu) - (y2 + Dd2 * uu)) * zarr[j];
        const size_t oi = gbase + (size_t)t * DIN;
        ushort hh = f2bf(v);
        yd_hi[oi] = hh;
        yd_lo[oi] = f2bf(v - bf2f(hh));
      }
    }
  }
}

// =====================================================================
extern "C" void kernel_launch(void* const* d_in, const int* in_sizes, int n_in,
                              void* d_out, int out_size, void* d_ws, size_t ws_size,
                              hipStream_t stream) {
  const float* hidden = (const float*)d_in[0];
  const float* in_proj_w = (const float*)d_in[1];
  const float* conv_w = (const float*)d_in[2];
  const float* conv_b = (const float*)d_in[3];
  const float* x1w = (const float*)d_in[4];
  const float* dtw1 = (const float*)d_in[5];
  const float* dtb1 = (const float*)d_in[6];
  const float* Al1 = (const float*)d_in[7];
  const float* D1 = (const float*)d_in[8];
  const float* x2w = (const float*)d_in[9];
  const float* dtw2 = (const float*)d_in[10];
  const float* dtb2 = (const float*)d_in[11];
  const float* Al2 = (const float*)d_in[12];
  const float* D2 = (const float*)d_in[13];
  const float* outw = (const float*)d_in[14];
  float* out = (float*)d_out;

  // Workspace layout (floats), 34.47M = 137.9 MB (same as proven rounds 5-8).
  float* ws = (float*)d_ws;
  float* xz = ws;                                   // 8.39M  (x rows, z rows)
  float* xcTbuf = xz + (size_t)4096 * SEQ;          // 4.19M  xcT bf16 hi/lo planes
  float* dblS = xcTbuf + (size_t)SEQ * DIN;         // 393K
  float* sp1T = dblS + (size_t)192 * SEQ;           // 4.19M  softplus'd dt, (l,d)
  float* sp2T = sp1T + (size_t)SEQ * DIN;           // 4.19M
  float* y1t = sp2T + (size_t)SEQ * DIN;            // 4.19M  -> zT (l,d) fp32
  float* y2t = y1t + (size_t)SEQ * DIN;             // 4.19M  -> yd bf16 planes
  float* hend = y2t + (size_t)SEQ * DIN;            // 2.10M
  float* Pend = hend + (size_t)2 * NCH * DIN * NST; // 2.10M (reused as hin)
  float* BT1 = Pend + (size_t)2 * NCH * DIN * NST;  // 32K each
  float* CT1 = BT1 + (size_t)SEQ * NST;
  float* BT2 = CT1 + (size_t)SEQ * NST;
  float* CT2 = BT2 + (size_t)SEQ * NST;
  float* wxp = CT2 + (size_t)SEQ * NST;             // 393K stacked x_proj W planes

  float* dbl1 = dblS;
  float* dbl2 = dblS + (size_t)96 * SEQ;

  // Aliases (lifetime-disjoint):
  ushort* xcT_hi = (ushort*)xcTbuf;                 // steps 3..7 (u planes)
  ushort* xcT_lo = (ushort*)(xcTbuf + 2097152);
  ushort* w_hi = (ushort*)y1t;                      // in_proj_w planes (dead after step 2)
  ushort* w_lo = (ushort*)(y1t + 2097152);
  ushort* h_hi = (ushort*)y2t;                      // hidden planes (dead after step 2)
  ushort* h_lo = (ushort*)(y2t + 1048576);
  ushort* wx_hi = (ushort*)wxp;                     // stacked x_proj weights 192x2048
  ushort* wx_lo = (ushort*)(wxp + 196608);
  float* xp_part = sp1T;                            // 8 slabs x 192*2048 = 3.15M < 4.19M
  float* zT = y1t;                                  // silu(z) (l,d) fp32 (after step 2)
  ushort* yd_hi = (ushort*)y2t;                     // ydiff planes (h planes dead)
  ushort* yd_lo = (ushort*)(y2t + 2097152);
  // outw planes fit EXACTLY inside hend's 2.10M floats (dead after carry).
  ushort* ow_hi = (ushort*)hend;
  ushort* ow_lo = (ushort*)(hend + 1048576);
  float* opart = xz;                                // out_proj split-K partials (xz dead after z_tr)

  dim3 blk(256);

  // 1) fused split-convert: in_proj_w, hidden, x1w, x2w
  cvt_fused<<<dim3(6528), blk, 0, stream>>>(in_proj_w, hidden, x1w, x2w,
                                            w_hi, w_lo, h_hi, h_lo, wx_hi, wx_lo);

  // 2) in_proj via 3-pass bf16 MFMA -> xz (e,l)
  gemm3p<128, 128, 1><<<dim3(SEQ / 128, 4096 / 128, 1), blk, 0, stream>>>(
      w_hi, w_lo, h_hi, h_lo, xz, 4096, SEQ, DMODEL);

  // 3) conv + silu -> xcT bf16 hi/lo planes (l,d);  silu(z) -> zT fp32 (l,d)
  conv_tr_kernel<<<dim3(SEQ / 64, DIN / 64), blk, 0, stream>>>(
      xz, conv_w, conv_b, xcT_hi, xcT_lo);
  z_tr_kernel<<<dim3(SEQ / 64, DIN / 64), blk, 0, stream>>>(xz, zT);

  // 4) x_proj via MFMA, split-K=8 (both branches stacked, M=192)
  gemm3p<64, 128, 8><<<dim3(SEQ / 128, 192 / 64, 8), blk, 0, stream>>>(
      wx_hi, wx_lo, xcT_hi, xcT_lo, xp_part, 192, SEQ, DIN);

  // 5) reduce slabs -> dblS + B/C transpose tables
  reduce_dblS_kernel<<<dim3(192 * SEQ / 256), blk, 0, stream>>>(
      xp_part, dblS, BT1, CT1, BT2, CT2);

  // 6) dt projection + fused softplus -> sp planes, (l,d)
  dt_gemm_kernel<<<dim3(SEQ / 64, DIN / 64, 2), blk, 0, stream>>>(
      dbl1, dbl2, dtw1, dtw2, dtb1, dtb2, sp1T, sp2T);

  // 7) chunked selective scan (A both branches; C fused -> yd planes)
  scan_phase_a<<<dim3(DIN / 256, NCH, 2), blk, 0, stream>>>(
      xcT_hi, xcT_lo, sp1T, sp2T, BT1, BT2, Al1, Al2, hend, Pend);
  scan_carry<<<dim3(2 * DIN * NST / 256), blk, 0, stream>>>(hend, Pend);
  cvt_split<<<dim3(2048), blk, 0, stream>>>(outw, ow_hi, ow_lo, DMODEL * DIN);
  scan_phase_c_fused<<<dim3(DIN / 256, NCH), blk, 0, stream>>>(
      xcT_hi, xcT_lo, sp1T, sp2T, BT1, CT1, BT2, CT2, Al1, Al2, D1, D2,
      Pend, zT, yd_hi, yd_lo);

  // 8) out_proj via 3-pass bf16 MFMA, split-K=4
  gemm3p<128, 128, 4><<<dim3(DMODEL / 128, SEQ / 128, 4), blk, 0, stream>>>(
      yd_hi, yd_lo, ow_hi, ow_lo, opart, SEQ, DMODEL, DIN);
  reduce_out<<<dim3(SEQ * DMODEL / 1024), blk, 0, stream>>>(opart, out, SEQ * DMODEL);
}

// Round 10
// 329.092 us; speedup vs baseline: 1.0466x; 1.0466x over previous
//
#include <hip/hip_runtime.h>
#include <math.h>

#define SEQ 2048
#define DMODEL 1024
#define DIN 2048
#define NST 16
#define DTR 64
#define CH 64
#define NCH (SEQ / CH)

typedef __attribute__((ext_vector_type(8))) short bf16x8;
typedef __attribute__((ext_vector_type(4))) float f32x4;

__device__ __forceinline__ ushort f2bf(float f) {
  union { float f; unsigned u; } c; c.f = f;
  return (ushort)((c.u + 0x7fffu + ((c.u >> 16) & 1u)) >> 16);
}
__device__ __forceinline__ float bf2f(ushort h) {
  union { unsigned u; float f; } c; c.u = ((unsigned)h) << 16;
  return c.f;
}
__device__ __forceinline__ float splus(float v) {
  return v > 20.f ? v : log1pf(__expf(v));
}
// p[n] = e^(n+1), depth-4 mul tree (no transcendentals).
__device__ __forceinline__ void powers16(float e, float* p) {
  float e2 = e * e, e4 = e2 * e2, e8 = e4 * e4;
  p[0] = e;       p[1] = e2;       p[2] = e2 * e;   p[3] = e4;
  p[4] = e4 * e;  p[5] = e4 * e2;  p[6] = e4 * p[2]; p[7] = e8;
  p[8] = e8 * e;  p[9] = e8 * e2;  p[10] = e8 * p[2]; p[11] = e8 * e4;
  p[12] = e8 * p[4]; p[13] = e8 * p[5]; p[14] = e8 * p[6]; p[15] = e8 * e8;
}

#define GLL(g, l) __builtin_amdgcn_global_load_lds( \
    (const __attribute__((address_space(1))) void*)(g), \
    (__attribute__((address_space(3))) void*)(l), 16, 0, 0)

// =====================================================================
// Split-bf16 MFMA GEMM.  C[m,n]=sum_k A[m,k]B[n,k]
// MODE 0: full 3-pass (fp32-accurate).
// MODE 1: blocks with m0 >= msplit drop A_lo (2-pass: Ahi*Bhi + Ahi*Blo).
// MODE 2: drop B_lo everywhere (2-pass: Ahi*Bhi + Alo*Bhi).
// Staging: burst-coalesced global lane map + XOR swizzle of the 16B
// k-chunk (phys = c ^ ((r>>1)&3)); fragment reads 2-way = free.
// =====================================================================
template<int BM, int BN, int SPLITK, int MODE>
__global__ __launch_bounds__(256) void gemm3p(const ushort* __restrict__ Ahi,
                                              const ushort* __restrict__ Alo,
                                              const ushort* __restrict__ Bhi,
                                              const ushort* __restrict__ Blo,
                                              float* __restrict__ C,
                                              int M, int N, int K, int msplit) {
  constexpr int BK = 32;
  constexpr int WM = BM / 2, WN = BN / 2, TM = WM / 16, TN = WN / 16;
  constexpr int SA = BM / 16, SB = BN / 16;
  __shared__ __align__(16) ushort sAh[BM * BK], sAl[BM * BK];
  __shared__ __align__(16) ushort sBh[BN * BK], sBl[BN * BK];
  const int tid = threadIdx.x, wid = tid >> 6, lane = tid & 63;
  const int m0 = blockIdx.y * BM, n0 = blockIdx.x * BN;
  const int Kc = K / SPLITK, kbeg = blockIdx.z * Kc;
  const int wm0 = (wid >> 1) * WM, wn0 = (wid & 1) * WN;
  const int fr = lane & 15;
  const int lrow = lane >> 2;
  const int lkc = (lane & 3) ^ ((lane >> 3) & 3);
  const int fpo = fr * 32 + (((lane >> 4) ^ ((lane >> 1) & 3)) * 8);
  const bool dropA = (MODE == 1) && (m0 >= msplit);
  const bool dropB = (MODE == 2);

  f32x4 acc[TM][TN];
#pragma unroll
  for (int mi = 0; mi < TM; ++mi)
#pragma unroll
    for (int ni = 0; ni < TN; ++ni)
#pragma unroll
      for (int r = 0; r < 4; ++r) acc[mi][ni][r] = 0.f;

  for (int k0 = 0; k0 < Kc; k0 += BK) {
    __syncthreads();
    const int kg = kbeg + k0 + lkc * 8;
#pragma unroll
    for (int i = 0; i < SA / 4; ++i) {
      const int seg = wid * (SA / 4) + i;
      const size_t ga = (size_t)(m0 + seg * 16 + lrow) * K + kg;
      GLL(&Ahi[ga], &sAh[seg * 512]);
      if (!dropA) GLL(&Alo[ga], &sAl[seg * 512]);
    }
#pragma unroll
    for (int i = 0; i < SB / 4; ++i) {
      const int seg = wid * (SB / 4) + i;
      const size_t ga = (size_t)(n0 + seg * 16 + lrow) * K + kg;
      GLL(&Bhi[ga], &sBh[seg * 512]);
      if (!dropB) GLL(&Blo[ga], &sBl[seg * 512]);
    }
    __syncthreads();

    bf16x8 ah[TM], al[TM], bh[TN], bl[TN];
#pragma unroll
    for (int mi = 0; mi < TM; ++mi) {
      const int r = (wm0 / 16 + mi) * 512 + fpo;
      ah[mi] = *(const bf16x8*)&sAh[r];
      if (!dropA) al[mi] = *(const bf16x8*)&sAl[r];
    }
#pragma unroll
    for (int ni = 0; ni < TN; ++ni) {
      const int r = (wn0 / 16 + ni) * 512 + fpo;
      bh[ni] = *(const bf16x8*)&sBh[r];
      if (!dropB) bl[ni] = *(const bf16x8*)&sBl[r];
    }
#pragma unroll
    for (int mi = 0; mi < TM; ++mi)
#pragma unroll
      for (int ni = 0; ni < TN; ++ni) {
        acc[mi][ni] = __builtin_amdgcn_mfma_f32_16x16x32_bf16(ah[mi], bh[ni], acc[mi][ni], 0, 0, 0);
        if (!dropB)
          acc[mi][ni] = __builtin_amdgcn_mfma_f32_16x16x32_bf16(ah[mi], bl[ni], acc[mi][ni], 0, 0, 0);
        if (!dropA)
          acc[mi][ni] = __builtin_amdgcn_mfma_f32_16x16x32_bf16(al[mi], bh[ni], acc[mi][ni], 0, 0, 0);
      }
  }

  float* __restrict__ Co = C + (size_t)blockIdx.z * M * N;
#pragma unroll
  for (int mi = 0; mi < TM; ++mi)
#pragma unroll
    for (int ni = 0; ni < TN; ++ni)
#pragma unroll
      for (int r = 0; r < 4; ++r)
        Co[(size_t)(m0 + wm0 + mi * 16 + (lane >> 4) * 4 + r) * N + n0 + wn0 + ni * 16 + fr] =
            acc[mi][ni][r];
}

__device__ __forceinline__ void split_store4(float4 v, ushort* hi, ushort* lo, size_t i) {
  ushort h0 = f2bf(v.x), h1 = f2bf(v.y), h2 = f2bf(v.z), h3 = f2bf(v.w);
  *(ushort4*)&hi[i] = make_ushort4(h0, h1, h2, h3);
  *(ushort4*)&lo[i] = make_ushort4(f2bf(v.x - bf2f(h0)), f2bf(v.y - bf2f(h1)),
                                   f2bf(v.z - bf2f(h2)), f2bf(v.w - bf2f(h3)));
}

// One launch converting in_proj_w, hidden, x1w, x2w -> bf16 hi/lo planes.
__global__ __launch_bounds__(256) void cvt_fused(const float* __restrict__ inw,
                                                 const float* __restrict__ hid,
                                                 const float* __restrict__ x1w,
                                                 const float* __restrict__ x2w,
                                                 ushort* __restrict__ w_hi, ushort* __restrict__ w_lo,
                                                 ushort* __restrict__ h_hi, ushort* __restrict__ h_lo,
                                                 ushort* __restrict__ wx_hi, ushort* __restrict__ wx_lo) {
  const int q = blockIdx.x * 256 + threadIdx.x;  // float4 index
  const float* src; ushort* dhi; ushort* dlo; int base;
  if (q < 1048576)            { src = inw; dhi = w_hi;  dlo = w_lo;  base = q; }
  else if (q < 1572864)       { src = hid; dhi = h_hi;  dlo = h_lo;  base = q - 1048576; }
  else if (q < 1622016)       { src = x1w; dhi = wx_hi; dlo = wx_lo; base = q - 1572864; }
  else                        { src = x2w; dhi = wx_hi + 196608; dlo = wx_lo + 196608; base = q - 1622016; }
  const size_t i = (size_t)base * 4;
  split_store4(*(const float4*)&src[i], dhi, dlo, i);
}

__global__ __launch_bounds__(256) void reduce_out(const float* __restrict__ p,
                                                  float* __restrict__ o, int n) {
  const int i = (blockIdx.x * 256 + threadIdx.x) * 4;
  if (i >= n) return;
  float4 a = *(const float4*)&p[i];
  float4 b = *(const float4*)&p[(size_t)n + i];
  float4 c = *(const float4*)&p[(size_t)2 * n + i];
  float4 d = *(const float4*)&p[(size_t)3 * n + i];
  *(float4*)&o[i] = make_float4(a.x + b.x + c.x + d.x, a.y + b.y + c.y + d.y,
                                a.z + b.z + c.z + d.z, a.w + b.w + c.w + d.w);
}

// =====================================================================
// Conv (w=4, causal) + bias + SiLU -> transposed bf16 hi/lo planes (l,d).
// =====================================================================
__global__ __launch_bounds__(256) void conv_tr_kernel(const float* __restrict__ xz,
                                                      const float* __restrict__ cw,
                                                      const float* __restrict__ cb,
                                                      ushort* __restrict__ xcT_hi,
                                                      ushort* __restrict__ xcT_lo) {
  const int l0 = blockIdx.x * 64, d0 = blockIdx.y * 64;
  const int tid = threadIdx.x;
  __shared__ float xin[64][68];  // cols 0..66 = l0-3 .. l0+63
  __shared__ float To[64][65];
  __shared__ float cwS[64][4];
  __shared__ float cbS[64];

  for (int i = tid; i < 1024; i += 256) {
    const int d = i >> 4, q = i & 15;
    float4 v = *(const float4*)&xz[(size_t)(d0 + d) * SEQ + l0 + q * 4];
    xin[d][3 + q * 4 + 0] = v.x; xin[d][3 + q * 4 + 1] = v.y;
    xin[d][3 + q * 4 + 2] = v.z; xin[d][3 + q * 4 + 3] = v.w;
  }
  if (tid < 192) {
    const int j = tid >> 6, d = tid & 63;
    const int l = l0 - 3 + j;
    xin[d][j] = (l >= 0) ? xz[(size_t)(d0 + d) * SEQ + l] : 0.f;
  }
  if (tid < 64) {
    cbS[tid] = cb[d0 + tid];
    float4 w = *(const float4*)&cw[(d0 + tid) * 4];
    cwS[tid][0] = w.x; cwS[tid][1] = w.y; cwS[tid][2] = w.z; cwS[tid][3] = w.w;
  }
  __syncthreads();

  for (int i = tid; i < 4096; i += 256) {
    const int d = i >> 6, l = i & 63;
    float a = cbS[d] + cwS[d][0] * xin[d][l] + cwS[d][1] * xin[d][l + 1] +
              cwS[d][2] * xin[d][l + 2] + cwS[d][3] * xin[d][l + 3];
    To[d][l] = a / (1.f + __expf(-a));
  }
  __syncthreads();

  for (int i = tid; i < 4096; i += 256) {
    const int l = i >> 6, dd = i & 63;
    float v = To[dd][l];  // stride-65: conflict-free
    ushort h = f2bf(v);
    xcT_hi[(size_t)(l0 + l) * DIN + d0 + dd] = h;
    xcT_lo[(size_t)(l0 + l) * DIN + d0 + dd] = f2bf(v - bf2f(h));
  }
}

// (y1raw - y2raw) * silu(z), tiled with LDS transpose of z; -> bf16 planes.
__global__ __launch_bounds__(256) void ydiff_tr_kernel(const float* __restrict__ y1,
                                                       const float* __restrict__ y2,
                                                       const float* __restrict__ xz,
                                                       ushort* __restrict__ hi,
                                                       ushort* __restrict__ lo) {
  const int l0 = blockIdx.x * 64, d0 = blockIdx.y * 64;
  const int tid = threadIdx.x;
  __shared__ float Tz[64][65];
  for (int i = tid; i < 1024; i += 256) {
    const int d = i >> 4, q = i & 15;
    float4 v = *(const float4*)&xz[(size_t)(DIN + d0 + d) * SEQ + l0 + q * 4];
    Tz[d][q * 4 + 0] = v.x / (1.f + __expf(-v.x));
    Tz[d][q * 4 + 1] = v.y / (1.f + __expf(-v.y));
    Tz[d][q * 4 + 2] = v.z / (1.f + __expf(-v.z));
    Tz[d][q * 4 + 3] = v.w / (1.f + __expf(-v.w));
  }
  __syncthreads();
  for (int i = tid; i < 1024; i += 256) {
    const int l = i >> 4, dc = (i & 15) * 4;
    const size_t g = (size_t)(l0 + l) * DIN + d0 + dc;
    float4 a = *(const float4*)&y1[g];
    float4 b = *(const float4*)&y2[g];
    float4 v = make_float4((a.x - b.x) * Tz[dc + 0][l], (a.y - b.y) * Tz[dc + 1][l],
                           (a.z - b.z) * Tz[dc + 2][l], (a.w - b.w) * Tz[dc + 3][l]);
    split_store4(v, hi, lo, g);
  }
}

// Reduce 8 x_proj split-K slabs (192 x SEQ) -> dblS; emit B/C (l,n) tables.
__global__ __launch_bounds__(256) void reduce_dblS_kernel(const float* __restrict__ p,
                                                          float* __restrict__ o,
                                                          float* __restrict__ BT1,
                                                          float* __restrict__ CT1,
                                                          float* __restrict__ BT2,
                                                          float* __restrict__ CT2) {
  const int NE = 192 * SEQ;
  const int idx = blockIdx.x * 256 + threadIdx.x;
  float s = 0.f;
#pragma unroll
  for (int cc = 0; cc < 8; ++cc) s += p[(size_t)cc * NE + idx];
  o[idx] = s;
  const int k = idx >> 11, l = idx & (SEQ - 1);
  if (k >= 64 && k < 80)        BT1[l * NST + (k - 64)] = s;
  else if (k >= 80 && k < 96)   CT1[l * NST + (k - 80)] = s;
  else if (k >= 160 && k < 176) BT2[l * NST + (k - 160)] = s;
  else if (k >= 176)            CT2[l * NST + (k - 176)] = s;
}

// =====================================================================
// dt GEMM + fused softplus(dt+bias); output sp in (l,d) layout.
// =====================================================================
__global__ __launch_bounds__(256) void dt_gemm_kernel(const float* __restrict__ dbl1,
                                                      const float* __restrict__ dbl2,
                                                      const float* __restrict__ w1,
                                                      const float* __restrict__ w2,
                                                      const float* __restrict__ b1,
                                                      const float* __restrict__ b2,
                                                      float* __restrict__ o1,
                                                      float* __restrict__ o2) {
  const int br = blockIdx.z;
  const float* __restrict__ dbl = br ? dbl2 : dbl1;
  const float* __restrict__ W = br ? w2 : w1;
  const float* __restrict__ dtb = br ? b2 : b1;
  float* __restrict__ outp = br ? o2 : o1;
  const int l0 = blockIdx.x * 64, d0 = blockIdx.y * 64;
  __shared__ __align__(16) float Wt[64][68];
  __shared__ __align__(16) float Bs[64][68];
  const int tid = threadIdx.x;
  for (int i = tid; i < 4096; i += 256) {
    int a = i >> 6, b = i & 63;
    Wt[b][a] = W[(size_t)(d0 + a) * DTR + b];
    Bs[a][b] = dbl[(size_t)a * SEQ + l0 + b];
  }
  __syncthreads();
  const int tl_ = tid >> 4, td_ = tid & 15;
  float acc[4][4];  // [i: l][j: d]
#pragma unroll
  for (int i = 0; i < 4; ++i)
#pragma unroll
    for (int j = 0; j < 4; ++j) acc[i][j] = 0.f;
  for (int r = 0; r < 64; ++r) {
    float4 av = *(const float4*)&Bs[r][tl_ * 4];
    float4 bv = *(const float4*)&Wt[r][td_ * 4];
    float am[4] = {av.x, av.y, av.z, av.w};
    float bn[4] = {bv.x, bv.y, bv.z, bv.w};
#pragma unroll
    for (int i = 0; i < 4; ++i)
#pragma unroll
      for (int j = 0; j < 4; ++j) acc[i][j] = fmaf(am[i], bn[j], acc[i][j]);
  }
  const float4 bias4 = *(const float4*)&dtb[d0 + td_ * 4];
#pragma unroll
  for (int i = 0; i < 4; ++i) {
    float4 w = make_float4(splus(acc[i][0] + bias4.x), splus(acc[i][1] + bias4.y),
                           splus(acc[i][2] + bias4.z), splus(acc[i][3] + bias4.w));
    *(float4*)&outp[(size_t)(l0 + tl_ * 4 + i) * DIN + d0 + td_ * 4] = w;
  }
}

// =====================================================================
// Chunked selective scan.  All per-timestep inputs in (l,d) layout ->
// coalesced scalar loads.  u = hi+lo bf16 reconstruction (2^-18 exact).
// dA_n = exp(-k_n*sp); fast path when k_n == n+1 (one exp + mul tree).
// =====================================================================
__global__ __launch_bounds__(256) void scan_phase_a(const ushort* __restrict__ uhi,
                                                    const ushort* __restrict__ ulo,
                                                    const float* __restrict__ sp1T,
                                                    const float* __restrict__ sp2T,
                                                    const float* __restrict__ BT1,
                                                    const float* __restrict__ BT2,
                                                    const float* __restrict__ Al1,
                                                    const float* __restrict__ Al2,
                                                    float* __restrict__ hend,
                                                    float* __restrict__ Pend) {
  const int br = blockIdx.z;
  const float* __restrict__ spp = br ? sp2T : sp1T;
  const float* __restrict__ BT = br ? BT2 : BT1;
  const float* __restrict__ Al = br ? Al2 : Al1;
  const int c = blockIdx.y;
  const int t0 = c * CH;
  const int d = blockIdx.x * 256 + threadIdx.x;
  const size_t gbase = (size_t)t0 * DIN + d;

  __shared__ __align__(16) float Bs[CH][NST];
  ((float4*)Bs)[threadIdx.x] = ((const float4*)&BT[t0 * NST])[threadIdx.x];
  __syncthreads();

  bool fast = true;
#pragma unroll
  for (int n = 0; n < NST; ++n) {
    float kx = __expf(Al[(size_t)d * NST + n]);
    fast = fast && (fabsf(kx - (float)(n + 1)) < 1e-3f);
  }
  float h[NST];
#pragma unroll
  for (int n = 0; n < NST; ++n) h[n] = 0.f;
  float S = 0.f;

  if (fast) {
    for (int tt = 0; tt < CH / 4; ++tt) {
      float sparr[4], uarr[4];
#pragma unroll
      for (int j = 0; j < 4; ++j) {
        const size_t idx = gbase + (size_t)(tt * 4 + j) * DIN;
        sparr[j] = spp[idx];
        uarr[j] = bf2f(uhi[idx]) + bf2f(ulo[idx]);
      }
#pragma unroll
      for (int j = 0; j < 4; ++j) {
        const int t = tt * 4 + j;
        const float sp = sparr[j];
        S += sp;
        const float spu = sp * uarr[j];
        const float e = __expf(-sp);
        float p[NST];
        powers16(e, p);
#pragma unroll
        for (int ng = 0; ng < 4; ++ng) {
          float4 bq = *(const float4*)&Bs[t][ng * 4];
          float bf[4] = {bq.x, bq.y, bq.z, bq.w};
#pragma unroll
          for (int k = 0; k < 4; ++k) {
            int n = ng * 4 + k;
            h[n] = fmaf(p[n], h[n], spu * bf[k]);
          }
        }
      }
    }
  } else {
    float AnL2[NST];
#pragma unroll
    for (int n = 0; n < NST; ++n)
      AnL2[n] = -__expf(Al[(size_t)d * NST + n]) * 1.4426950408889634f;
    for (int tt = 0; tt < CH / 4; ++tt) {
      float sparr[4], uarr[4];
#pragma unroll
      for (int j = 0; j < 4; ++j) {
        const size_t idx = gbase + (size_t)(tt * 4 + j) * DIN;
        sparr[j] = spp[idx];
        uarr[j] = bf2f(uhi[idx]) + bf2f(ulo[idx]);
      }
#pragma unroll
      for (int j = 0; j < 4; ++j) {
        const int t = tt * 4 + j;
        const float sp = sparr[j];
        S += sp;
        const float spu = sp * uarr[j];
#pragma unroll
        for (int ng = 0; ng < 4; ++ng) {
          float4 bq = *(const float4*)&Bs[t][ng * 4];
          float bf[4] = {bq.x, bq.y, bq.z, bq.w};
#pragma unroll
          for (int k = 0; k < 4; ++k) {
            int n = ng * 4 + k;
            float dA = exp2f(AnL2[n] * sp);
            h[n] = fmaf(dA, h[n], spu * bf[k]);
          }
        }
      }
    }
  }

  float P[NST];
  if (fast) {
    powers16(__expf(-S), P);
  } else {
#pragma unroll
    for (int n = 0; n < NST; ++n)
      P[n] = exp2f(-__expf(Al[(size_t)d * NST + n]) * 1.4426950408889634f * S);
  }
  size_t base = ((size_t)(br * NCH + c) * DIN + d) * NST;
#pragma unroll
  for (int n = 0; n < NST; n += 4) {
    *(float4*)&hend[base + n] = make_float4(h[n], h[n + 1], h[n + 2], h[n + 3]);
    *(float4*)&Pend[base + n] = make_float4(P[n], P[n + 1], P[n + 2], P[n + 3]);
  }
}

// Merged: blocks [0,256) do the chunk-carry (hin overwrites Pend in place);
// blocks [256,2304) split-convert outw -> ow_hi plane (lo dropped: out_proj
// runs 2-pass).  Regions are disjoint (reads hend, writes Pend + ow in xz).
__global__ __launch_bounds__(256) void carry_cvt(const float* __restrict__ hend,
                                                 float* __restrict__ PendHin,
                                                 const float* __restrict__ outw,
                                                 ushort* __restrict__ ow_hi) {
  const int b = blockIdx.x;
  if (b < 256) {
    const int flat = b * 256 + threadIdx.x;
    const int br = flat >> 15;
    const int dn = flat & 32767;
    float h = 0.f;
    for (int c = 0; c < NCH; ++c) {
      size_t idx = ((size_t)(br * NCH + c) << 15) + dn;
      float Pv = PendHin[idx];
      float he = hend[idx];
      PendHin[idx] = h;
      h = fmaf(Pv, h, he);
    }
  } else {
    const size_t i = ((size_t)(b - 256) * 256 + threadIdx.x) * 4;  // < 2,097,152
    float4 v = *(const float4*)&outw[i];
    *(ushort4*)&ow_hi[i] = make_ushort4(f2bf(v.x), f2bf(v.y), f2bf(v.z), f2bf(v.w));
  }
}

// Phase C: raw y (silu(z) applied later in ydiff_tr), (l,d) writes.
__global__ __launch_bounds__(256) void scan_phase_c(const ushort* __restrict__ uhi,
                                                    const ushort* __restrict__ ulo,
                                                    const float* __restrict__ sp1T,
                                                    const float* __restrict__ sp2T,
                                                    const float* __restrict__ BT1,
                                                    const float* __restrict__ CT1,
                                                    const float* __restrict__ BT2,
                                                    const float* __restrict__ CT2,
                                                    const float* __restrict__ Al1,
                                                    const float* __restrict__ Al2,
                                                    const float* __restrict__ D1,
                                                    const float* __restrict__ D2,
                                                    const float* __restrict__ hin,
                                                    float* __restrict__ y1t,
                                                    float* __restrict__ y2t) {
  const int br = blockIdx.z;
  const float* __restrict__ spp = br ? sp2T : sp1T;
  const float* __restrict__ BT = br ? BT2 : BT1;
  const float* __restrict__ CT = br ? CT2 : CT1;
  const float* __restrict__ Al = br ? Al2 : Al1;
  const float* __restrict__ Dp = br ? D2 : D1;
  float* __restrict__ yt = br ? y2t : y1t;
  const int c = blockIdx.y;
  const int t0 = c * CH;
  const int d = blockIdx.x * 256 + threadIdx.x;
  const size_t gbase = (size_t)t0 * DIN + d;

  __shared__ __align__(16) float Bs[CH][NST];
  __shared__ __align__(16) float Cs[CH][NST];
  ((float4*)Bs)[threadIdx.x] = ((const float4*)&BT[t0 * NST])[threadIdx.x];
  ((float4*)Cs)[threadIdx.x] = ((const float4*)&CT[t0 * NST])[threadIdx.x];
  __syncthreads();

  bool fast = true;
#pragma unroll
  for (int n = 0; n < NST; ++n) {
    float kx = __expf(Al[(size_t)d * NST + n]);
    fast = fast && (fabsf(kx - (float)(n + 1)) < 1e-3f);
  }
  const float Dd = Dp[d];
  float h[NST];
  const size_t hbase = ((size_t)(br * NCH + c) * DIN + d) * NST;
#pragma unroll
  for (int n = 0; n < NST; n += 4) {
    float4 hv = *(const float4*)&hin[hbase + n];
    h[n] = hv.x; h[n + 1] = hv.y; h[n + 2] = hv.z; h[n + 3] = hv.w;
  }

  if (fast) {
    for (int tt = 0; tt < CH / 4; ++tt) {
      float sparr[4], uarr[4];
#pragma unroll
      for (int j = 0; j < 4; ++j) {
        const size_t idx = gbase + (size_t)(tt * 4 + j) * DIN;
        sparr[j] = spp[idx];
        uarr[j] = bf2f(uhi[idx]) + bf2f(ulo[idx]);
      }
#pragma unroll
      for (int j = 0; j < 4; ++j) {
        const int t = tt * 4 + j;
        const float sp = sparr[j];
        const float spu = sp * uarr[j];
        const float e = __expf(-sp);
        float p[NST];
        powers16(e, p);
        float y = 0.f;
#pragma unroll
        for (int ng = 0; ng < 4; ++ng) {
          float4 bq = *(const float4*)&Bs[t][ng * 4];
          float4 cq = *(const float4*)&Cs[t][ng * 4];
          float bf[4] = {bq.x, bq.y, bq.z, bq.w};
          float cf[4] = {cq.x, cq.y, cq.z, cq.w};
#pragma unroll
          for (int k = 0; k < 4; ++k) {
            int n = ng * 4 + k;
            h[n] = fmaf(p[n], h[n], spu * bf[k]);
            y = fmaf(h[n], cf[k], y);
          }
        }
        yt[gbase + (size_t)t * DIN] = y + Dd * uarr[j];
      }
    }
  } else {
    float AnL2[NST];
#pragma unroll
    for (int n = 0; n < NST; ++n)
      AnL2[n] = -__expf(Al[(size_t)d * NST + n]) * 1.4426950408889634f;
    for (int tt = 0; tt < CH / 4; ++tt) {
      float sparr[4], uarr[4];
#pragma unroll
      for (int j = 0; j < 4; ++j) {
        const size_t idx = gbase + (size_t)(tt * 4 + j) * DIN;
        sparr[j] = spp[idx];
        uarr[j] = bf2f(uhi[idx]) + bf2f(ulo[idx]);
      }
#pragma unroll
      for (int j = 0; j < 4; ++j) {
        const int t = tt * 4 + j;
        const float sp = sparr[j];
        const float spu = sp * uarr[j];
        float y = 0.f;
#pragma unroll
        for (int ng = 0; ng < 4; ++ng) {
          float4 bq = *(const float4*)&Bs[t][ng * 4];
          float4 cq = *(const float4*)&Cs[t][ng * 4];
          float bf[4] = {bq.x, bq.y, bq.z, bq.w};
          float cf[4] = {cq.x, cq.y, cq.z, cq.w};
#pragma unroll
          for (int k = 0; k < 4; ++k) {
            int n = ng * 4 + k;
            float dA = exp2f(AnL2[n] * sp);
            h[n] = fmaf(dA, h[n], spu * bf[k]);
            y = fmaf(h[n], cf[k], y);
          }
        }
        yt[gbase + (size_t)t * DIN] = y + Dd * uarr[j];
      }
    }
  }
}

// =====================================================================
extern "C" void kernel_launch(void* const* d_in, const int* in_sizes, int n_in,
                              void* d_out, int out_size, void* d_ws, size_t ws_size,
                              hipStream_t stream) {
  const float* hidden = (const float*)d_in[0];
  const float* in_proj_w = (const float*)d_in[1];
  const float* conv_w = (const float*)d_in[2];
  const float* conv_b = (const float*)d_in[3];
  const float* x1w = (const float*)d_in[4];
  const float* dtw1 = (const float*)d_in[5];
  const float* dtb1 = (const float*)d_in[6];
  const float* Al1 = (const float*)d_in[7];
  const float* D1 = (const float*)d_in[8];
  const float* x2w = (const float*)d_in[9];
  const float* dtw2 = (const float*)d_in[10];
  const float* dtb2 = (const float*)d_in[11];
  const float* Al2 = (const float*)d_in[12];
  const float* D2 = (const float*)d_in[13];
  const float* outw = (const float*)d_in[14];
  float* out = (float*)d_out;

  // Workspace layout (floats), 34.47M = 137.9 MB (same as proven rounds 5-9).
  float* ws = (float*)d_ws;
  float* xz = ws;                                   // 8.39M  (x rows, z rows)
  float* xcTbuf = xz + (size_t)4096 * SEQ;          // 4.19M  xcT bf16 hi/lo planes
  float* dblS = xcTbuf + (size_t)SEQ * DIN;         // 393K
  float* sp1T = dblS + (size_t)192 * SEQ;           // 4.19M  softplus'd dt, (l,d)
  float* sp2T = sp1T + (size_t)SEQ * DIN;           // 4.19M
  float* y1t = sp2T + (size_t)SEQ * DIN;            // 4.19M  (l,d) raw y
  float* y2t = y1t + (size_t)SEQ * DIN;             // 4.19M
  float* hend = y2t + (size_t)SEQ * DIN;            // 2.10M
  float* Pend = hend + (size_t)2 * NCH * DIN * NST; // 2.10M (reused as hin)
  float* BT1 = Pend + (size_t)2 * NCH * DIN * NST;  // 32K each
  float* CT1 = BT1 + (size_t)SEQ * NST;
  float* BT2 = CT1 + (size_t)SEQ * NST;
  float* CT2 = BT2 + (size_t)SEQ * NST;
  float* wxp = CT2 + (size_t)SEQ * NST;             // 393K stacked x_proj W planes

  float* dbl1 = dblS;
  float* dbl2 = dblS + (size_t)96 * SEQ;

  // Aliases (lifetime-disjoint):
  ushort* xcT_hi = (ushort*)xcTbuf;                 // u planes, steps 3..7
  ushort* xcT_lo = (ushort*)(xcTbuf + 2097152);
  ushort* w_hi = (ushort*)y1t;                      // in_proj_w planes (dead after step 2)
  ushort* w_lo = (ushort*)(y1t + 2097152);
  ushort* h_hi = (ushort*)y2t;                      // hidden planes (dead after step 2)
  ushort* h_lo = (ushort*)(y2t + 1048576);
  ushort* wx_hi = (ushort*)wxp;                     // stacked x_proj weights 192x2048
  ushort* wx_lo = (ushort*)(wxp + 196608);
  float* xp_part = sp1T;                            // 8 slabs x 192*2048 = 3.15M < 4.19M
  ushort* yd_hi = (ushort*)xcTbuf;                  // ydiff planes (xcT dead after phase C)
  ushort* yd_lo = (ushort*)(xcTbuf + 2097152);
  // outw hi plane -> xz x-half (x rows dead after conv_tr); z rows untouched.
  ushort* ow_hi = (ushort*)xz;
  // out_proj split-K partials -> sp1T..sp2T (8.39M; sp dead after phase C).
  float* opart = sp1T;

  dim3 blk(256);

  // 1) fused split-convert: in_proj_w, hidden, x1w, x2w
  cvt_fused<<<dim3(6528), blk, 0, stream>>>(in_proj_w, hidden, x1w, x2w,
                                            w_hi, w_lo, h_hi, h_lo, wx_hi, wx_lo);

  // 2) in_proj via bf16 MFMA -> xz (e,l).  x rows (m<2048) 3-pass;
  //    z rows (m>=2048) 2-pass (drop w_lo: z only feeds silu-multiply).
  gemm3p<128, 128, 1, 1><<<dim3(SEQ / 128, 4096 / 128, 1), blk, 0, stream>>>(
      w_hi, w_lo, h_hi, h_lo, xz, 4096, SEQ, DMODEL, 2048);

  // 3) conv + silu -> xcT bf16 hi/lo planes (l,d)
  conv_tr_kernel<<<dim3(SEQ / 64, DIN / 64), blk, 0, stream>>>(
      xz, conv_w, conv_b, xcT_hi, xcT_lo);

  // 4) x_proj via MFMA 3-pass, split-K=8 (both branches stacked, M=192)
  gemm3p<64, 128, 8, 0><<<dim3(SEQ / 128, 192 / 64, 8), blk, 0, stream>>>(
      wx_hi, wx_lo, xcT_hi, xcT_lo, xp_part, 192, SEQ, DIN, 0x7fffffff);

  // 5) reduce slabs -> dblS + B/C transpose tables
  reduce_dblS_kernel<<<dim3(192 * SEQ / 256), blk, 0, stream>>>(
      xp_part, dblS, BT1, CT1, BT2, CT2);

  // 6) dt projection + fused softplus -> sp planes, (l,d)
  dt_gemm_kernel<<<dim3(SEQ / 64, DIN / 64, 2), blk, 0, stream>>>(
      dbl1, dbl2, dtw1, dtw2, dtb1, dtb2, sp1T, sp2T);

  // 7) chunked selective scan; carry merged with outw hi-plane convert
  scan_phase_a<<<dim3(DIN / 256, NCH, 2), blk, 0, stream>>>(
      xcT_hi, xcT_lo, sp1T, sp2T, BT1, BT2, Al1, Al2, hend, Pend);
  carry_cvt<<<dim3(2304), blk, 0, stream>>>(hend, Pend, outw, ow_hi);
  scan_phase_c<<<dim3(DIN / 256, NCH, 2), blk, 0, stream>>>(
      xcT_hi, xcT_lo, sp1T, sp2T, BT1, CT1, BT2, CT2, Al1, Al2, D1, D2, Pend, y1t, y2t);

  // 8) (y1-y2)*silu(z) -> bf16 planes (tiled transpose of z)
  ydiff_tr_kernel<<<dim3(SEQ / 64, DIN / 64), blk, 0, stream>>>(
      y1t, y2t, xz, yd_hi, yd_lo);

  // 9) out_proj via bf16 MFMA 2-pass (drop outw_lo), split-K=4
  gemm3p<128, 128, 4, 2><<<dim3(DMODEL / 128, SEQ / 128, 4), blk, 0, stream>>>(
      yd_hi, yd_lo, ow_hi, ow_hi, opart, SEQ, DMODEL, DIN, 0x7fffffff);
  reduce_out<<<dim3(SEQ * DMODEL / 1024), blk, 0, stream>>>(opart, out, SEQ * DMODEL);
}

// Round 12
// 327.548 us; speedup vs baseline: 1.0515x; 1.0047x over previous
//
#include <hip/hip_runtime.h>
#include <math.h>

#define SEQ 2048
#define DMODEL 1024
#define DIN 2048
#define NST 16
#define DTR 64
#define CH 64
#define NCH (SEQ / CH)

typedef __attribute__((ext_vector_type(8))) short bf16x8;
typedef __attribute__((ext_vector_type(4))) float f32x4;

__device__ __forceinline__ ushort f2bf(float f) {
  union { float f; unsigned u; } c; c.f = f;
  return (ushort)((c.u + 0x7fffu + ((c.u >> 16) & 1u)) >> 16);
}
__device__ __forceinline__ float bf2f(ushort h) {
  union { unsigned u; float f; } c; c.u = ((unsigned)h) << 16;
  return c.f;
}
__device__ __forceinline__ float splus(float v) {
  return v > 20.f ? v : log1pf(__expf(v));
}
// p[n] = e^(n+1), depth-4 mul tree (no transcendentals).
__device__ __forceinline__ void powers16(float e, float* p) {
  float e2 = e * e, e4 = e2 * e2, e8 = e4 * e4;
  p[0] = e;       p[1] = e2;       p[2] = e2 * e;   p[3] = e4;
  p[4] = e4 * e;  p[5] = e4 * e2;  p[6] = e4 * p[2]; p[7] = e8;
  p[8] = e8 * e;  p[9] = e8 * e2;  p[10] = e8 * p[2]; p[11] = e8 * e4;
  p[12] = e8 * p[4]; p[13] = e8 * p[5]; p[14] = e8 * p[6]; p[15] = e8 * e8;
}

#define GLL(g, l) __builtin_amdgcn_global_load_lds( \
    (const __attribute__((address_space(1))) void*)(g), \
    (__attribute__((address_space(3))) void*)(l), 16, 0, 0)

// =====================================================================
// Split-bf16 MFMA GEMM.  C[m,n]=sum_k A[m,k]B[n,k]
// MODE 0: full 3-pass (fp32-accurate).
// MODE 2: drop B_lo everywhere (compile-time 2-pass: Ahi*Bhi + Alo*Bhi).
// (no runtime mode switches: round-10 showed they inflate VGPR 88->112
//  and drop MfmaUtil 35->27%)
// Staging: burst-coalesced global lane map + XOR swizzle of the 16B
// k-chunk (phys = c ^ ((r>>1)&3)); fragment reads 2-way = free.
// =====================================================================
template<int BM, int BN, int SPLITK, int MODE>
__global__ __launch_bounds__(256) void gemm3p(const ushort* __restrict__ Ahi,
                                              const ushort* __restrict__ Alo,
                                              const ushort* __restrict__ Bhi,
                                              const ushort* __restrict__ Blo,
                                              float* __restrict__ C,
                                              int M, int N, int K) {
  constexpr int BK = 32;
  constexpr int WM = BM / 2, WN = BN / 2, TM = WM / 16, TN = WN / 16;
  constexpr int SA = BM / 16, SB = BN / 16;
  constexpr bool dropB = (MODE == 2);
  __shared__ __align__(16) ushort sAh[BM * BK], sAl[BM * BK];
  __shared__ __align__(16) ushort sBh[BN * BK], sBl[BN * BK];
  const int tid = threadIdx.x, wid = tid >> 6, lane = tid & 63;
  const int m0 = blockIdx.y * BM, n0 = blockIdx.x * BN;
  const int Kc = K / SPLITK, kbeg = blockIdx.z * Kc;
  const int wm0 = (wid >> 1) * WM, wn0 = (wid & 1) * WN;
  const int fr = lane & 15;
  const int lrow = lane >> 2;
  const int lkc = (lane & 3) ^ ((lane >> 3) & 3);
  const int fpo = fr * 32 + (((lane >> 4) ^ ((lane >> 1) & 3)) * 8);

  f32x4 acc[TM][TN];
#pragma unroll
  for (int mi = 0; mi < TM; ++mi)
#pragma unroll
    for (int ni = 0; ni < TN; ++ni)
#pragma unroll
      for (int r = 0; r < 4; ++r) acc[mi][ni][r] = 0.f;

  for (int k0 = 0; k0 < Kc; k0 += BK) {
    __syncthreads();
    const int kg = kbeg + k0 + lkc * 8;
#pragma unroll
    for (int i = 0; i < SA / 4; ++i) {
      const int seg = wid * (SA / 4) + i;
      const size_t ga = (size_t)(m0 + seg * 16 + lrow) * K + kg;
      GLL(&Ahi[ga], &sAh[seg * 512]);
      GLL(&Alo[ga], &sAl[seg * 512]);
    }
#pragma unroll
    for (int i = 0; i < SB / 4; ++i) {
      const int seg = wid * (SB / 4) + i;
      const size_t ga = (size_t)(n0 + seg * 16 + lrow) * K + kg;
      GLL(&Bhi[ga], &sBh[seg * 512]);
      if (!dropB) GLL(&Blo[ga], &sBl[seg * 512]);
    }
    __syncthreads();

    bf16x8 ah[TM], al[TM], bh[TN], bl[TN];
#pragma unroll
    for (int mi = 0; mi < TM; ++mi) {
      const int r = (wm0 / 16 + mi) * 512 + fpo;
      ah[mi] = *(const bf16x8*)&sAh[r];
      al[mi] = *(const bf16x8*)&sAl[r];
    }
#pragma unroll
    for (int ni = 0; ni < TN; ++ni) {
      const int r = (wn0 / 16 + ni) * 512 + fpo;
      bh[ni] = *(const bf16x8*)&sBh[r];
      if (!dropB) bl[ni] = *(const bf16x8*)&sBl[r];
    }
#pragma unroll
    for (int mi = 0; mi < TM; ++mi)
#pragma unroll
      for (int ni = 0; ni < TN; ++ni) {
        acc[mi][ni] = __builtin_amdgcn_mfma_f32_16x16x32_bf16(ah[mi], bh[ni], acc[mi][ni], 0, 0, 0);
        if (!dropB)
          acc[mi][ni] = __builtin_amdgcn_mfma_f32_16x16x32_bf16(ah[mi], bl[ni], acc[mi][ni], 0, 0, 0);
        acc[mi][ni] = __builtin_amdgcn_mfma_f32_16x16x32_bf16(al[mi], bh[ni], acc[mi][ni], 0, 0, 0);
      }
  }

  float* __restrict__ Co = C + (size_t)blockIdx.z * M * N;
#pragma unroll
  for (int mi = 0; mi < TM; ++mi)
#pragma unroll
    for (int ni = 0; ni < TN; ++ni)
#pragma unroll
      for (int r = 0; r < 4; ++r)
        Co[(size_t)(m0 + wm0 + mi * 16 + (lane >> 4) * 4 + r) * N + n0 + wn0 + ni * 16 + fr] =
            acc[mi][ni][r];
}

__device__ __forceinline__ void split_store4(float4 v, ushort* hi, ushort* lo, size_t i) {
  ushort h0 = f2bf(v.x), h1 = f2bf(v.y), h2 = f2bf(v.z), h3 = f2bf(v.w);
  *(ushort4*)&hi[i] = make_ushort4(h0, h1, h2, h3);
  *(ushort4*)&lo[i] = make_ushort4(f2bf(v.x - bf2f(h0)), f2bf(v.y - bf2f(h1)),
                                   f2bf(v.z - bf2f(h2)), f2bf(v.w - bf2f(h3)));
}

// One launch converting in_proj_w, hidden, x1w, x2w -> bf16 hi/lo planes.
__global__ __launch_bounds__(256) void cvt_fused(const float* __restrict__ inw,
                                                 const float* __restrict__ hid,
                                                 const float* __restrict__ x1w,
                                                 const float* __restrict__ x2w,
                                                 ushort* __restrict__ w_hi, ushort* __restrict__ w_lo,
                                                 ushort* __restrict__ h_hi, ushort* __restrict__ h_lo,
                                                 ushort* __restrict__ wx_hi, ushort* __restrict__ wx_lo) {
  const int q = blockIdx.x * 256 + threadIdx.x;  // float4 index
  const float* src; ushort* dhi; ushort* dlo; int base;
  if (q < 1048576)            { src = inw; dhi = w_hi;  dlo = w_lo;  base = q; }
  else if (q < 1572864)       { src = hid; dhi = h_hi;  dlo = h_lo;  base = q - 1048576; }
  else if (q < 1622016)       { src = x1w; dhi = wx_hi; dlo = wx_lo; base = q - 1572864; }
  else                        { src = x2w; dhi = wx_hi + 196608; dlo = wx_lo + 196608; base = q - 1622016; }
  const size_t i = (size_t)base * 4;
  split_store4(*(const float4*)&src[i], dhi, dlo, i);
}

__global__ __launch_bounds__(256) void reduce_out(const float* __restrict__ p,
                                                  float* __restrict__ o, int n) {
  const int i = (blockIdx.x * 256 + threadIdx.x) * 4;
  if (i >= n) return;
  float4 a = *(const float4*)&p[i];
  float4 b = *(const float4*)&p[(size_t)n + i];
  float4 c = *(const float4*)&p[(size_t)2 * n + i];
  float4 d = *(const float4*)&p[(size_t)3 * n + i];
  *(float4*)&o[i] = make_float4(a.x + b.x + c.x + d.x, a.y + b.y + c.y + d.y,
                                a.z + b.z + c.z + d.z, a.w + b.w + c.w + d.w);
}

// =====================================================================
// Conv (w=4, causal) + bias + SiLU -> transposed bf16 hi/lo planes (l,d).
// =====================================================================
__global__ __launch_bounds__(256) void conv_tr_kernel(const float* __restrict__ xz,
                                                      const float* __restrict__ cw,
                                                      const float* __restrict__ cb,
                                                      ushort* __restrict__ xcT_hi,
                                                      ushort* __restrict__ xcT_lo) {
  const int l0 = blockIdx.x * 64, d0 = blockIdx.y * 64;
  const int tid = threadIdx.x;
  __shared__ float xin[64][68];  // cols 0..66 = l0-3 .. l0+63
  __shared__ float To[64][65];
  __shared__ float cwS[64][4];
  __shared__ float cbS[64];

  for (int i = tid; i < 1024; i += 256) {
    const int d = i >> 4, q = i & 15;
    float4 v = *(const float4*)&xz[(size_t)(d0 + d) * SEQ + l0 + q * 4];
    xin[d][3 + q * 4 + 0] = v.x; xin[d][3 + q * 4 + 1] = v.y;
    xin[d][3 + q * 4 + 2] = v.z; xin[d][3 + q * 4 + 3] = v.w;
  }
  if (tid < 192) {
    const int j = tid >> 6, d = tid & 63;
    const int l = l0 - 3 + j;
    xin[d][j] = (l >= 0) ? xz[(size_t)(d0 + d) * SEQ + l] : 0.f;
  }
  if (tid < 64) {
    cbS[tid] = cb[d0 + tid];
    float4 w = *(const float4*)&cw[(d0 + tid) * 4];
    cwS[tid][0] = w.x; cwS[tid][1] = w.y; cwS[tid][2] = w.z; cwS[tid][3] = w.w;
  }
  __syncthreads();

  for (int i = tid; i < 4096; i += 256) {
    const int d = i >> 6, l = i & 63;
    float a = cbS[d] + cwS[d][0] * xin[d][l] + cwS[d][1] * xin[d][l + 1] +
              cwS[d][2] * xin[d][l + 2] + cwS[d][3] * xin[d][l + 3];
    To[d][l] = a / (1.f + __expf(-a));
  }
  __syncthreads();

  for (int i = tid; i < 4096; i += 256) {
    const int l = i >> 6, dd = i & 63;
    float v = To[dd][l];  // stride-65: conflict-free
    ushort h = f2bf(v);
    xcT_hi[(size_t)(l0 + l) * DIN + d0 + dd] = h;
    xcT_lo[(size_t)(l0 + l) * DIN + d0 + dd] = f2bf(v - bf2f(h));
  }
}

// (y1raw - y2raw) * silu(z), tiled with LDS transpose of z; -> bf16 planes.
__global__ __launch_bounds__(256) void ydiff_tr_kernel(const float* __restrict__ y1,
                                                       const float* __restrict__ y2,
                                                       const float* __restrict__ xz,
                                                       ushort* __restrict__ hi,
                                                       ushort* __restrict__ lo) {
  const int l0 = blockIdx.x * 64, d0 = blockIdx.y * 64;
  const int tid = threadIdx.x;
  __shared__ float Tz[64][65];
  for (int i = tid; i < 1024; i += 256) {
    const int d = i >> 4, q = i & 15;
    float4 v = *(const float4*)&xz[(size_t)(DIN + d0 + d) * SEQ + l0 + q * 4];
    Tz[d][q * 4 + 0] = v.x / (1.f + __expf(-v.x));
    Tz[d][q * 4 + 1] = v.y / (1.f + __expf(-v.y));
    Tz[d][q * 4 + 2] = v.z / (1.f + __expf(-v.z));
    Tz[d][q * 4 + 3] = v.w / (1.f + __expf(-v.w));
  }
  __syncthreads();
  for (int i = tid; i < 1024; i += 256) {
    const int l = i >> 4, dc = (i & 15) * 4;
    const size_t g = (size_t)(l0 + l) * DIN + d0 + dc;
    float4 a = *(const float4*)&y1[g];
    float4 b = *(const float4*)&y2[g];
    float4 v = make_float4((a.x - b.x) * Tz[dc + 0][l], (a.y - b.y) * Tz[dc + 1][l],
                           (a.z - b.z) * Tz[dc + 2][l], (a.w - b.w) * Tz[dc + 3][l]);
    split_store4(v, hi, lo, g);
  }
}

// Reduce 8 x_proj split-K slabs (192 x SEQ) -> dblS; emit B/C (l,n) tables.
__global__ __launch_bounds__(256) void reduce_dblS_kernel(const float* __restrict__ p,
                                                          float* __restrict__ o,
                                                          float* __restrict__ BT1,
                                                          float* __restrict__ CT1,
                                                          float* __restrict__ BT2,
                                                          float* __restrict__ CT2) {
  const int NE = 192 * SEQ;
  const int idx = blockIdx.x * 256 + threadIdx.x;
  float s = 0.f;
#pragma unroll
  for (int cc = 0; cc < 8; ++cc) s += p[(size_t)cc * NE + idx];
  o[idx] = s;
  const int k = idx >> 11, l = idx & (SEQ - 1);
  if (k >= 64 && k < 80)        BT1[l * NST + (k - 64)] = s;
  else if (k >= 80 && k < 96)   CT1[l * NST + (k - 80)] = s;
  else if (k >= 160 && k < 176) BT2[l * NST + (k - 160)] = s;
  else if (k >= 176)            CT2[l * NST + (k - 176)] = s;
}

// =====================================================================
// dt GEMM + fused softplus(dt+bias); output sp in (l,d) layout.
// =====================================================================
__global__ __launch_bounds__(256) void dt_gemm_kernel(const float* __restrict__ dbl1,
                                                      const float* __restrict__ dbl2,
                                                      const float* __restrict__ w1,
                                                      const float* __restrict__ w2,
                                                      const float* __restrict__ b1,
                                                      const float* __restrict__ b2,
                                                      float* __restrict__ o1,
                                                      float* __restrict__ o2) {
  const int br = blockIdx.z;
  const float* __restrict__ dbl = br ? dbl2 : dbl1;
  const float* __restrict__ W = br ? w2 : w1;
  const float* __restrict__ dtb = br ? b2 : b1;
  float* __restrict__ outp = br ? o2 : o1;
  const int l0 = blockIdx.x * 64, d0 = blockIdx.y * 64;
  __shared__ __align__(16) float Wt[64][68];
  __shared__ __align__(16) float Bs[64][68];
  const int tid = threadIdx.x;
  for (int i = tid; i < 4096; i += 256) {
    int a = i >> 6, b = i & 63;
    Wt[b][a] = W[(size_t)(d0 + a) * DTR + b];
    Bs[a][b] = dbl[(size_t)a * SEQ + l0 + b];
  }
  __syncthreads();
  const int tl_ = tid >> 4, td_ = tid & 15;
  float acc[4][4];  // [i: l][j: d]
#pragma unroll
  for (int i = 0; i < 4; ++i)
#pragma unroll
    for (int j = 0; j < 4; ++j) acc[i][j] = 0.f;
  for (int r = 0; r < 64; ++r) {
    float4 av = *(const float4*)&Bs[r][tl_ * 4];
    float4 bv = *(const float4*)&Wt[r][td_ * 4];
    float am[4] = {av.x, av.y, av.z, av.w};
    float bn[4] = {bv.x, bv.y, bv.z, bv.w};
#pragma unroll
    for (int i = 0; i < 4; ++i)
#pragma unroll
      for (int j = 0; j < 4; ++j) acc[i][j] = fmaf(am[i], bn[j], acc[i][j]);
  }
  const float4 bias4 = *(const float4*)&dtb[d0 + td_ * 4];
#pragma unroll
  for (int i = 0; i < 4; ++i) {
    float4 w = make_float4(splus(acc[i][0] + bias4.x), splus(acc[i][1] + bias4.y),
                           splus(acc[i][2] + bias4.z), splus(acc[i][3] + bias4.w));
    *(float4*)&outp[(size_t)(l0 + tl_ * 4 + i) * DIN + d0 + td_ * 4] = w;
  }
}

// =====================================================================
// Chunked selective scan.  All per-timestep inputs in (l,d) layout ->
// coalesced scalar loads.  u = hi+lo bf16 reconstruction (2^-18 exact).
// dA_n = exp(-k_n*sp); fast path when k_n == n+1 (one exp + mul tree).
// =====================================================================
__global__ __launch_bounds__(256) void scan_phase_a(const ushort* __restrict__ uhi,
                                                    const ushort* __restrict__ ulo,
                                                    const float* __restrict__ sp1T,
                                                    const float* __restrict__ sp2T,
                                                    const float* __restrict__ BT1,
                                                    const float* __restrict__ BT2,
                                                    const float* __restrict__ Al1,
                                                    const float* __restrict__ Al2,
                                                    float* __restrict__ hend,
                                                    float* __restrict__ Pend) {
  const int br = blockIdx.z;
  const float* __restrict__ spp = br ? sp2T : sp1T;
  const float* __restrict__ BT = br ? BT2 : BT1;
  const float* __restrict__ Al = br ? Al2 : Al1;
  const int c = blockIdx.y;
  const int t0 = c * CH;
  const int d = blockIdx.x * 256 + threadIdx.x;
  const size_t gbase = (size_t)t0 * DIN + d;

  __shared__ __align__(16) float Bs[CH][NST];
  ((float4*)Bs)[threadIdx.x] = ((const float4*)&BT[t0 * NST])[threadIdx.x];
  __syncthreads();

  bool fast = true;
#pragma unroll
  for (int n = 0; n < NST; ++n) {
    float kx = __expf(Al[(size_t)d * NST + n]);
    fast = fast && (fabsf(kx - (float)(n + 1)) < 1e-3f);
  }
  float h[NST];
#pragma unroll
  for (int n = 0; n < NST; ++n) h[n] = 0.f;
  float S = 0.f;

  if (fast) {
    for (int tt = 0; tt < CH / 4; ++tt) {
      float sparr[4], uarr[4];
#pragma unroll
      for (int j = 0; j < 4; ++j) {
        const size_t idx = gbase + (size_t)(tt * 4 + j) * DIN;
        sparr[j] = spp[idx];
        uarr[j] = bf2f(uhi[idx]) + bf2f(ulo[idx]);
      }
#pragma unroll
      for (int j = 0; j < 4; ++j) {
        const int t = tt * 4 + j;
        const float sp = sparr[j];
        S += sp;
        const float spu = sp * uarr[j];
        const float e = __expf(-sp);
        float p[NST];
        powers16(e, p);
#pragma unroll
        for (int ng = 0; ng < 4; ++ng) {
          float4 bq = *(const float4*)&Bs[t][ng * 4];
          float bf[4] = {bq.x, bq.y, bq.z, bq.w};
#pragma unroll
          for (int k = 0; k < 4; ++k) {
            int n = ng * 4 + k;
            h[n] = fmaf(p[n], h[n], spu * bf[k]);
          }
        }
      }
    }
  } else {
    float AnL2[NST];
#pragma unroll
    for (int n = 0; n < NST; ++n)
      AnL2[n] = -__expf(Al[(size_t)d * NST + n]) * 1.4426950408889634f;
    for (int tt = 0; tt < CH / 4; ++tt) {
      float sparr[4], uarr[4];
#pragma unroll
      for (int j = 0; j < 4; ++j) {
        const size_t idx = gbase + (size_t)(tt * 4 + j) * DIN;
        sparr[j] = spp[idx];
        uarr[j] = bf2f(uhi[idx]) + bf2f(ulo[idx]);
      }
#pragma unroll
      for (int j = 0; j < 4; ++j) {
        const int t = tt * 4 + j;
        const float sp = sparr[j];
        S += sp;
        const float spu = sp * uarr[j];
#pragma unroll
        for (int ng = 0; ng < 4; ++ng) {
          float4 bq = *(const float4*)&Bs[t][ng * 4];
          float bf[4] = {bq.x, bq.y, bq.z, bq.w};
#pragma unroll
          for (int k = 0; k < 4; ++k) {
            int n = ng * 4 + k;
            float dA = exp2f(AnL2[n] * sp);
            h[n] = fmaf(dA, h[n], spu * bf[k]);
          }
        }
      }
    }
  }

  float P[NST];
  if (fast) {
    powers16(__expf(-S), P);
  } else {
#pragma unroll
    for (int n = 0; n < NST; ++n)
      P[n] = exp2f(-__expf(Al[(size_t)d * NST + n]) * 1.4426950408889634f * S);
  }
  size_t base = ((size_t)(br * NCH + c) * DIN + d) * NST;
#pragma unroll
  for (int n = 0; n < NST; n += 4) {
    *(float4*)&hend[base + n] = make_float4(h[n], h[n + 1], h[n + 2], h[n + 3]);
    *(float4*)&Pend[base + n] = make_float4(P[n], P[n + 1], P[n + 2], P[n + 3]);
  }
}

// Merged: blocks [0,256) do the chunk-carry (hin overwrites Pend in place);
// blocks [256,2304) split-convert outw -> ow_hi plane (lo dropped: out_proj
// runs 2-pass).  Regions are disjoint (reads hend, writes Pend + ow in xz).
__global__ __launch_bounds__(256) void carry_cvt(const float* __restrict__ hend,
                                                 float* __restrict__ PendHin,
                                                 const float* __restrict__ outw,
                                                 ushort* __restrict__ ow_hi) {
  const int b = blockIdx.x;
  if (b < 256) {
    const int flat = b * 256 + threadIdx.x;
    const int br = flat >> 15;
    const int dn = flat & 32767;
    float h = 0.f;
    for (int c = 0; c < NCH; ++c) {
      size_t idx = ((size_t)(br * NCH + c) << 15) + dn;
      float Pv = PendHin[idx];
      float he = hend[idx];
      PendHin[idx] = h;
      h = fmaf(Pv, h, he);
    }
  } else {
    const size_t i = ((size_t)(b - 256) * 256 + threadIdx.x) * 4;  // < 2,097,152
    float4 v = *(const float4*)&outw[i];
    *(ushort4*)&ow_hi[i] = make_ushort4(f2bf(v.x), f2bf(v.y), f2bf(v.z), f2bf(v.w));
  }
}

// Phase C: raw y (silu(z) applied later in ydiff_tr), (l,d) writes.
__global__ __launch_bounds__(256) void scan_phase_c(const ushort* __restrict__ uhi,
                                                    const ushort* __restrict__ ulo,
                                                    const float* __restrict__ sp1T,
                                                    const float* __restrict__ sp2T,
                                                    const float* __restrict__ BT1,
                                                    const float* __restrict__ CT1,
                                                    const float* __restrict__ BT2,
                                                    const float* __restrict__ CT2,
                                                    const float* __restrict__ Al1,
                                                    const float* __restrict__ Al2,
                                                    const float* __restrict__ D1,
                                                    const float* __restrict__ D2,
                                                    const float* __restrict__ hin,
                                                    float* __restrict__ y1t,
                                                    float* __restrict__ y2t) {
  const int br = blockIdx.z;
  const float* __restrict__ spp = br ? sp2T : sp1T;
  const float* __restrict__ BT = br ? BT2 : BT1;
  const float* __restrict__ CT = br ? CT2 : CT1;
  const float* __restrict__ Al = br ? Al2 : Al1;
  const float* __restrict__ Dp = br ? D2 : D1;
  float* __restrict__ yt = br ? y2t : y1t;
  const int c = blockIdx.y;
  const int t0 = c * CH;
  const int d = blockIdx.x * 256 + threadIdx.x;
  const size_t gbase = (size_t)t0 * DIN + d;

  __shared__ __align__(16) float Bs[CH][NST];
  __shared__ __align__(16) float Cs[CH][NST];
  ((float4*)Bs)[threadIdx.x] = ((const float4*)&BT[t0 * NST])[threadIdx.x];
  ((float4*)Cs)[threadIdx.x] = ((const float4*)&CT[t0 * NST])[threadIdx.x];
  __syncthreads();

  bool fast = true;
#pragma unroll
  for (int n = 0; n < NST; ++n) {
    float kx = __expf(Al[(size_t)d * NST + n]);
    fast = fast && (fabsf(kx - (float)(n + 1)) < 1e-3f);
  }
  const float Dd = Dp[d];
  float h[NST];
  const size_t hbase = ((size_t)(br * NCH + c) * DIN + d) * NST;
#pragma unroll
  for (int n = 0; n < NST; n += 4) {
    float4 hv = *(const float4*)&hin[hbase + n];
    h[n] = hv.x; h[n + 1] = hv.y; h[n + 2] = hv.z; h[n + 3] = hv.w;
  }

  if (fast) {
    for (int tt = 0; tt < CH / 4; ++tt) {
      float sparr[4], uarr[4];
#pragma unroll
      for (int j = 0; j < 4; ++j) {
        const size_t idx = gbase + (size_t)(tt * 4 + j) * DIN;
        sparr[j] = spp[idx];
        uarr[j] = bf2f(uhi[idx]) + bf2f(ulo[idx]);
      }
#pragma unroll
      for (int j = 0; j < 4; ++j) {
        const int t = tt * 4 + j;
        const float sp = sparr[j];
        const float spu = sp * uarr[j];
        const float e = __expf(-sp);
        float p[NST];
        powers16(e, p);
        float y = 0.f;
#pragma unroll
        for (int ng = 0; ng < 4; ++ng) {
          float4 bq = *(const float4*)&Bs[t][ng * 4];
          float4 cq = *(const float4*)&Cs[t][ng * 4];
          float bf[4] = {bq.x, bq.y, bq.z, bq.w};
          float cf[4] = {cq.x, cq.y, cq.z, cq.w};
#pragma unroll
          for (int k = 0; k < 4; ++k) {
            int n = ng * 4 + k;
            h[n] = fmaf(p[n], h[n], spu * bf[k]);
            y = fmaf(h[n], cf[k], y);
          }
        }
        yt[gbase + (size_t)t * DIN] = y + Dd * uarr[j];
      }
    }
  } else {
    float AnL2[NST];
#pragma unroll
    for (int n = 0; n < NST; ++n)
      AnL2[n] = -__expf(Al[(size_t)d * NST + n]) * 1.4426950408889634f;
    for (int tt = 0; tt < CH / 4; ++tt) {
      float sparr[4], uarr[4];
#pragma unroll
      for (int j = 0; j < 4; ++j) {
        const size_t idx = gbase + (size_t)(tt * 4 + j) * DIN;
        sparr[j] = spp[idx];
        uarr[j] = bf2f(uhi[idx]) + bf2f(ulo[idx]);
      }
#pragma unroll
      for (int j = 0; j < 4; ++j) {
        const int t = tt * 4 + j;
        const float sp = sparr[j];
        const float spu = sp * uarr[j];
        float y = 0.f;
#pragma unroll
        for (int ng = 0; ng < 4; ++ng) {
          float4 bq = *(const float4*)&Bs[t][ng * 4];
          float4 cq = *(const float4*)&Cs[t][ng * 4];
          float bf[4] = {bq.x, bq.y, bq.z, bq.w};
          float cf[4] = {cq.x, cq.y, cq.z, cq.w};
#pragma unroll
          for (int k = 0; k < 4; ++k) {
            int n = ng * 4 + k;
            float dA = exp2f(AnL2[n] * sp);
            h[n] = fmaf(dA, h[n], spu * bf[k]);
            y = fmaf(h[n], cf[k], y);
          }
        }
        yt[gbase + (size_t)t * DIN] = y + Dd * uarr[j];
      }
    }
  }
}

// =====================================================================
extern "C" void kernel_launch(void* const* d_in, const int* in_sizes, int n_in,
                              void* d_out, int out_size, void* d_ws, size_t ws_size,
                              hipStream_t stream) {
  const float* hidden = (const float*)d_in[0];
  const float* in_proj_w = (const float*)d_in[1];
  const float* conv_w = (const float*)d_in[2];
  const float* conv_b = (const float*)d_in[3];
  const float* x1w = (const float*)d_in[4];
  const float* dtw1 = (const float*)d_in[5];
  const float* dtb1 = (const float*)d_in[6];
  const float* Al1 = (const float*)d_in[7];
  const float* D1 = (const float*)d_in[8];
  const float* x2w = (const float*)d_in[9];
  const float* dtw2 = (const float*)d_in[10];
  const float* dtb2 = (const float*)d_in[11];
  const float* Al2 = (const float*)d_in[12];
  const float* D2 = (const float*)d_in[13];
  const float* outw = (const float*)d_in[14];
  float* out = (float*)d_out;

  // Workspace layout (floats), 34.47M = 137.9 MB (same as proven rounds 5-10).
  float* ws = (float*)d_ws;
  float* xz = ws;                                   // 8.39M  (x rows, z rows)
  float* xcTbuf = xz + (size_t)4096 * SEQ;          // 4.19M  xcT bf16 hi/lo planes
  float* dblS = xcTbuf + (size_t)SEQ * DIN;         // 393K
  float* sp1T = dblS + (size_t)192 * SEQ;           // 4.19M  softplus'd dt, (l,d)
  float* sp2T = sp1T + (size_t)SEQ * DIN;           // 4.19M
  float* y1t = sp2T + (size_t)SEQ * DIN;            // 4.19M  (l,d) raw y
  float* y2t = y1t + (size_t)SEQ * DIN;             // 4.19M
  float* hend = y2t + (size_t)SEQ * DIN;            // 2.10M
  float* Pend = hend + (size_t)2 * NCH * DIN * NST; // 2.10M (reused as hin)
  float* BT1 = Pend + (size_t)2 * NCH * DIN * NST;  // 32K each
  float* CT1 = BT1 + (size_t)SEQ * NST;
  float* BT2 = CT1 + (size_t)SEQ * NST;
  float* CT2 = BT2 + (size_t)SEQ * NST;
  float* wxp = CT2 + (size_t)SEQ * NST;             // 393K stacked x_proj W planes

  float* dbl1 = dblS;
  float* dbl2 = dblS + (size_t)96 * SEQ;

  // Aliases (lifetime-disjoint):
  ushort* xcT_hi = (ushort*)xcTbuf;                 // u planes, steps 3..scan C
  ushort* xcT_lo = (ushort*)(xcTbuf + 2097152);
  ushort* w_hi = (ushort*)y1t;                      // in_proj_w planes (dead after step 2)
  ushort* w_lo = (ushort*)(y1t + 2097152);
  ushort* h_hi = (ushort*)y2t;                      // hidden planes (dead after step 2)
  ushort* h_lo = (ushort*)(y2t + 1048576);
  ushort* wx_hi = (ushort*)wxp;                     // stacked x_proj weights 192x2048
  ushort* wx_lo = (ushort*)(wxp + 196608);
  float* xp_part = sp1T;                            // 8 slabs x 192*2048 = 3.15M < 4.19M
  ushort* yd_hi = (ushort*)xcTbuf;                  // ydiff planes (u dead after phase C)
  ushort* yd_lo = (ushort*)(xcTbuf + 2097152);
  ushort* ow_hi = (ushort*)xz;                      // outw hi plane in dead x-rows of xz
  float* opart = sp1T;                              // out_proj split-K partials (sp dead)

  dim3 blk(256);

  // 1) fused split-convert: in_proj_w, hidden, x1w, x2w
  cvt_fused<<<dim3(6528), blk, 0, stream>>>(in_proj_w, hidden, x1w, x2w,
                                            w_hi, w_lo, h_hi, h_lo, wx_hi, wx_lo);

  // 2) in_proj via clean 3-pass bf16 MFMA -> xz (e,l)
  gemm3p<128, 128, 1, 0><<<dim3(SEQ / 128, 4096 / 128, 1), blk, 0, stream>>>(
      w_hi, w_lo, h_hi, h_lo, xz, 4096, SEQ, DMODEL);

  // 3) conv + silu -> xcT bf16 hi/lo planes (l,d)
  conv_tr_kernel<<<dim3(SEQ / 64, DIN / 64), blk, 0, stream>>>(
      xz, conv_w, conv_b, xcT_hi, xcT_lo);

  // 4) x_proj via MFMA 3-pass, split-K=8 (both branches stacked, M=192)
  gemm3p<64, 128, 8, 0><<<dim3(SEQ / 128, 192 / 64, 8), blk, 0, stream>>>(
      wx_hi, wx_lo, xcT_hi, xcT_lo, xp_part, 192, SEQ, DIN);

  // 5) reduce slabs -> dblS + B/C transpose tables
  reduce_dblS_kernel<<<dim3(192 * SEQ / 256), blk, 0, stream>>>(
      xp_part, dblS, BT1, CT1, BT2, CT2);

  // 6) dt projection + fused softplus -> sp planes, (l,d)
  dt_gemm_kernel<<<dim3(SEQ / 64, DIN / 64, 2), blk, 0, stream>>>(
      dbl1, dbl2, dtw1, dtw2, dtb1, dtb2, sp1T, sp2T);

  // 7) chunked selective scan; carry merged with outw hi-plane convert
  scan_phase_a<<<dim3(DIN / 256, NCH, 2), blk, 0, stream>>>(
      xcT_hi, xcT_lo, sp1T, sp2T, BT1, BT2, Al1, Al2, hend, Pend);
  carry_cvt<<<dim3(2304), blk, 0, stream>>>(hend, Pend, outw, ow_hi);
  scan_phase_c<<<dim3(DIN / 256, NCH, 2), blk, 0, stream>>>(
      xcT_hi, xcT_lo, sp1T, sp2T, BT1, CT1, BT2, CT2, Al1, Al2, D1, D2, Pend, y1t, y2t);

  // 8) (y1-y2)*silu(z) -> bf16 planes (tiled transpose of z)
  ydiff_tr_kernel<<<dim3(SEQ / 64, DIN / 64), blk, 0, stream>>>(
      y1t, y2t, xz, yd_hi, yd_lo);

  // 9) out_proj via bf16 MFMA 2-pass (drop outw_lo), split-K=4
  gemm3p<128, 128, 4, 2><<<dim3(DMODEL / 128, SEQ / 128, 4), blk, 0, stream>>>(
      yd_hi, yd_lo, ow_hi, ow_hi, opart, SEQ, DMODEL, DIN);
  reduce_out<<<dim3(SEQ * DMODEL / 1024), blk, 0, stream>>>(opart, out, SEQ * DMODEL);
}